// Round 15
// baseline (1056.460 us; speedup 1.0000x reference)
//
#include <hip/hip_runtime.h>
#include <math.h>

// Problem constants
#define B_   2048
#define T_   256
#define E_   124
#define V_   65
#define E2_  248
#define R_   8               // batch rows per block (A rows 0-7; rows 8-15 zero)
#define NT_  512             // 8 waves
#define NB_  (B_ / R_)       // 256 blocks -> 1 per CU
#define NKC  4               // K chunks (124 padded to 128)
#define TCH  8               // timestep chunk for GX precompute
#define GXPS 504             // GXP row stride in shorts (124*4 + pad, 8B-aligned)

// ws offsets (unsigned shorts); identical layout to R13/R14 (validated)
#define WS_WX  0
#define WS_WM2 49152
#define WS_HH  98304
#define WS_WM  147456
#define WS_HD  163840               // W' = ln_g ∘ w_head
#define WS_END 174080

// LDS byte offsets (16B aligned)
#define HSTR 136
#define L_M   0         // 2176
#define L_HA  2176
#define L_HB  4352
#define L_ZR  6528      // 272 zero row
#define L_GXP 6800      // [8][8][504] shorts = 64512 -> 71312 (packed: [eo*4+g])
#define L_XE  71312     // [8][8][136] shorts = 17408 -> 88720
#define L_BRZ 88720     // 248 f -> 89712
#define L_BIN 89712     // 124 f
#define L_BHN 90208
#define L_BM  90704
#define L_WP  91200     // 128 f (pad zeroed) -> 91712
#define L_C1  91712     // 68 f
#define L_C2B 91984     // 68 f
#define L_ACC 92256     // [2][8][4] f = 256 -> 92512 (p/LN atomic accumulators)
#define L_IDX 92512     // 8192 -> 100704
#define SMEM_BYTES 100704

typedef __attribute__((ext_vector_type(8))) short short8v;
typedef __attribute__((ext_vector_type(4))) short short4v;
typedef __attribute__((ext_vector_type(4))) float float4v;

__device__ __forceinline__ unsigned short f2bf(float x) {
    unsigned u = __float_as_uint(x);
    unsigned r = (u + 0x7fffu + ((u >> 16) & 1u)) >> 16;
    return (unsigned short)r;
}
__device__ __forceinline__ float bf2f(unsigned short s) {
    return __uint_as_float(((unsigned)s) << 16);
}
__device__ __forceinline__ float sigmoid_f(float x) {
    return 1.0f / (1.0f + __expf(-x));
}
__device__ __forceinline__ float tanh_f(float x) {
    return 2.0f / (1.0f + __expf(-2.0f * x)) - 1.0f;
}

// identical to R13/R14 (validated)
__global__ void prep_weights(const float* __restrict__ w_ih,
                             const float* __restrict__ w_hh,
                             const float* __restrict__ w_m,
                             const float* __restrict__ w_head,
                             const float* __restrict__ ln_g,
                             unsigned short* __restrict__ ws) {
    for (int n = blockIdx.x * blockDim.x + threadIdx.x; n < WS_END;
         n += gridDim.x * blockDim.x) {
        const int r9 = n & 511;
        const int lane = r9 >> 3, j = r9 & 7;
        const int krel = (lane >> 4) * 8 + j;   // 0..31
        const int colrel = lane & 15;
        float w = 0.f;
        if (n < WS_WM2) {                       // WX: w_ih[:, 0:124]
            const int blk = n >> 9;
            const int c = blk & 3, tt = (blk >> 2) & 7, g = blk >> 5;
            const int k = c * 32 + krel, e = tt * 16 + colrel;
            if (k < E_ && e < E_) w = w_ih[(g * E_ + e) * E2_ + k];
        } else if (n < WS_HH) {                 // WM2: w_ih[:, 124:248]
            const int blk = (n - WS_WM2) >> 9;
            const int c = blk & 3, tt = (blk >> 2) & 7, g = blk >> 5;
            const int k = c * 32 + krel, e = tt * 16 + colrel;
            if (k < E_ && e < E_) w = w_ih[(g * E_ + e) * E2_ + E_ + k];
        } else if (n < WS_WM) {                 // HH: w_hh
            const int blk = (n - WS_HH) >> 9;
            const int c = blk & 3, tt = (blk >> 2) & 7, g = blk >> 5;
            const int k = c * 32 + krel, e = tt * 16 + colrel;
            if (k < E_ && e < E_) w = w_hh[(g * E_ + e) * E_ + k];
        } else if (n < WS_HD) {                 // WM: w_m (cand)
            const int blk = (n - WS_WM) >> 9;
            const int c = blk & 3, tt = blk >> 2;
            const int k = c * 32 + krel, e = tt * 16 + colrel;
            if (k < E_ && e < E_) w = w_m[e * E_ + k];
        } else {                                // HD: W' = ln_g ∘ w_head
            const int blk = (n - WS_HD) >> 9;
            const int c = blk & 3, tt = blk >> 2;
            const int k = c * 32 + krel, v = tt * 16 + colrel;
            if (k < E_ && v < V_) w = w_head[v * E_ + k] * ln_g[k];
        }
        ws[n] = f2bf(w);
    }
}

__global__ void __launch_bounds__(NT_, 2)
gru_main(const int* __restrict__ idx, const float* __restrict__ tok,
         const float* __restrict__ pos,
         const float* __restrict__ b_ih, const float* __restrict__ b_hh,
         const float* __restrict__ w_p, const float* __restrict__ b_p,
         const float* __restrict__ b_m,
         const float* __restrict__ ln_g, const float* __restrict__ ln_b,
         const float* __restrict__ w_head, const float* __restrict__ b_head,
         const unsigned short* __restrict__ ws, float* __restrict__ out) {
    extern __shared__ char smraw[];
    unsigned short* Ms = (unsigned short*)(smraw + L_M);
    unsigned short* ZRs = (unsigned short*)(smraw + L_ZR);
    unsigned short* GXP = (unsigned short*)(smraw + L_GXP);
    unsigned short* XEs = (unsigned short*)(smraw + L_XE);
    float* BRZs = (float*)(smraw + L_BRZ);
    float* BINs = (float*)(smraw + L_BIN);
    float* BHNs = (float*)(smraw + L_BHN);
    float* BMs = (float*)(smraw + L_BM);
    float* WPs = (float*)(smraw + L_WP);
    float* C1s = (float*)(smraw + L_C1);
    float* C2Bs = (float*)(smraw + L_C2B);
    float* ACCs = (float*)(smraw + L_ACC);   // [buf][r][q], q: 0=pdot 1=sum 2=sumsq
    int* IDXs = (int*)(smraw + L_IDX);

    const int tid = threadIdx.x;
    const int lane = tid & 63;
    const int wv = tid >> 6;
    const int b0 = blockIdx.x * R_;
    const int frow = lane & 15;
    const int fgrp = lane >> 4;
    const int eo = wv * 16 + frow;
    const bool act = (fgrp < 2) && (eo < E_);
    const bool hdw = (wv >= 2) && (wv < 7);
    const int vo = (wv - 2) * 16 + frow;

    // ---- one-time staging ----
    for (int i = tid; i < E2_; i += NT_) BRZs[i] = b_ih[i] + b_hh[i];
    for (int i = tid; i < E_; i += NT_) {
        BINs[i] = b_ih[E2_ + i];
        BHNs[i] = b_hh[E2_ + i];
        BMs[i] = b_m[i];
    }
    for (int i = tid; i < 128; i += NT_) WPs[i] = (i < E_) ? w_p[i] : 0.f;
    for (int v = tid; v < V_; v += NT_) {
        float s1 = 0.f, s2 = 0.f;
        for (int e = 0; e < E_; ++e) {
            const float w = w_head[v * E_ + e];
            s1 += ln_g[e] * w;
            s2 += ln_b[e] * w;
        }
        C1s[v] = s1;
        C2Bs[v] = s2 + b_head[v];
    }
    for (int i = tid; i < R_ * T_; i += NT_) IDXs[i] = idx[b0 * T_ + i];
    for (int i = tid; i < 3400; i += NT_) ((unsigned short*)smraw)[i] = 0;  // M,HA,HB,ZR
    for (int i = tid; i < TCH * R_ * HSTR; i += NT_) XEs[i] = 0;
    for (int i = tid; i < 64; i += NT_) ACCs[i] = 0.f;
    const float bp = b_p[0];

    // ---- permanent register caches: 128 VGPR (within the 256 granule) ----
    short8v hhf[3][NKC], wm2f[3][NKC], wmf[NKC], hdf[NKC];
#pragma unroll
    for (int g = 0; g < 3; ++g)
#pragma unroll
        for (int c = 0; c < NKC; ++c) {
            hhf[g][c]  = *(const short8v*)&ws[WS_HH  + ((g * 8 + wv) * NKC + c) * 512 + lane * 8];
            wm2f[g][c] = *(const short8v*)&ws[WS_WM2 + ((g * 8 + wv) * NKC + c) * 512 + lane * 8];
        }
    {
        const int ht = hdw ? (wv - 2) : 0;
#pragma unroll
        for (int c = 0; c < NKC; ++c) {
            wmf[c] = *(const short8v*)&ws[WS_WM + (wv * NKC + c) * 512 + lane * 8];
            hdf[c] = *(const short8v*)&ws[WS_HD + (ht * NKC + c) * 512 + lane * 8];
        }
    }

    const unsigned short* Mrow = (frow < 8) ? Ms + frow * HSTR : ZRs;
    const unsigned short* Xrow = (frow < 8) ? XEs + frow * HSTR : ZRs;
    const int xstep = (frow < 8) ? R_ * HSTR : 0;
    __syncthreads();

    float hnewv[4] = {0.f, 0.f, 0.f, 0.f};
    float candv[4] = {0.f, 0.f, 0.f, 0.f};
    float hdv[4] = {0.f, 0.f, 0.f, 0.f};

    for (int t = 0; t < T_; ++t) {
        unsigned short* Hw = (unsigned short*)(smraw + ((t & 1) ? L_HB : L_HA));
        const unsigned short* Hr = (const unsigned short*)(smraw + ((t & 1) ? L_HA : L_HB));
        const unsigned short* Hrow = (frow < 8) ? Hr + frow * HSTR : ZRs;
        const unsigned short* Hwrow = (frow < 8) ? (const unsigned short*)Hw + frow * HSTR : ZRs;

        // ===== chunk phase (every 8 steps): GX[t..t+7] = W_x @ x, packed =====
        if ((t & 7) == 0) {
#pragma unroll
            for (int p = 0; p < 4; ++p) {
                const int i = tid + p * NT_;
                if (i < TCH * R_ * 31) {
                    const int mt = i / 248;
                    const int rem = i - mt * 248;
                    const int rr = rem / 31, q = rem - (rem / 31) * 31;
                    const int token = IDXs[rr * T_ + t + mt];
                    const int k = q * 4;
                    const float4 tv = *(const float4*)&tok[token * E_ + k];
                    const float4 pv = *(const float4*)&pos[(t + mt) * E_ + k];
#pragma unroll
                    for (int jj = 0; jj < 4; ++jj) {
                        const float x = ((const float*)&tv)[jj] + ((const float*)&pv)[jj];
                        XEs[(mt * R_ + rr) * HSTR + k + jj] = f2bf(x);
                    }
                }
            }
            __syncthreads();
#pragma unroll
            for (int g = 0; g < 3; ++g) {
                short8v bx[NKC];
#pragma unroll
                for (int c = 0; c < NKC; ++c)
                    bx[c] = *(const short8v*)&ws[WS_WX + ((g * 8 + wv) * NKC + c) * 512 + lane * 8];
                for (int mt = 0; mt < TCH; ++mt) {
                    float4v ax = (float4v){0.f, 0.f, 0.f, 0.f};
#pragma unroll
                    for (int c = 0; c < NKC; ++c) {
                        const short8v a = *(const short8v*)&Xrow[mt * xstep + c * 32 + fgrp * 8];
                        ax = __builtin_amdgcn_mfma_f32_16x16x32_bf16(a, bx[c], ax, 0, 0, 0);
                    }
                    if (act) {
#pragma unroll
                        for (int j = 0; j < 4; ++j)
                            GXP[(mt * R_ + fgrp * 4 + j) * GXPS + eo * 4 + g] = f2bf(ax[j]);
                    }
                }
            }
            // GX consumed lane-locally (same lane wrote its own gate entries)
        }

        // ===== phase A: MFMAs + gates -> h_new + p/LN partials (atomic) =====
        {
            short8v am[NKC], ah[NKC];
#pragma unroll
            for (int c = 0; c < NKC; ++c) {
                am[c] = *(const short8v*)&Mrow[c * 32 + fgrp * 8];
                ah[c] = *(const short8v*)&Hrow[c * 32 + fgrp * 8];
            }
            float4v accm[3], acch[3];
#pragma unroll
            for (int g = 0; g < 3; ++g) {
                accm[g] = (float4v){0.f, 0.f, 0.f, 0.f};
                acch[g] = (float4v){0.f, 0.f, 0.f, 0.f};
            }
#pragma unroll
            for (int g = 0; g < 3; ++g)
#pragma unroll
                for (int c = 0; c < NKC; ++c) {
                    accm[g] = __builtin_amdgcn_mfma_f32_16x16x32_bf16(am[c], wm2f[g][c], accm[g], 0, 0, 0);
                    acch[g] = __builtin_amdgcn_mfma_f32_16x16x32_bf16(ah[c], hhf[g][c], acch[g], 0, 0, 0);
                }
            // zero the OTHER accumulator buffer for step t+1 (read by C(t-1) already)
            if (tid < 32) ACCs[(((t + 1) & 1) << 5) + tid] = 0.f;

            if (act) {
                const float brz0 = BRZs[eo], brz1 = BRZs[E_ + eo];
                const float bin = BINs[eo], bhn = BHNs[eo];
                const int gxbase = ((t & 7) * R_) * GXPS + eo * 4;
#pragma unroll
                for (int j = 0; j < 4; ++j) {
                    const int r = fgrp * 4 + j;
                    const short4v gx4 = *(const short4v*)&GXP[gxbase + j * GXPS + (fgrp * 4) * GXPS];
                    const float rg = sigmoid_f(bf2f((unsigned short)gx4[0]) + accm[0][j] + acch[0][j] + brz0);
                    const float z = sigmoid_f(bf2f((unsigned short)gx4[1]) + accm[1][j] + acch[1][j] + brz1);
                    const float nn = tanh_f(bf2f((unsigned short)gx4[2]) + accm[2][j] + bin + rg * (acch[2][j] + bhn));
                    const float hold = bf2f(Hr[r * HSTR + eo]);
                    const float hv = (1.0f - z) * nn + z * hold;
                    hnewv[j] = hv;
                    Hw[r * HSTR + eo] = f2bf(hv);
                }
            }
            // in-wave p/LN partial reduce over the 16 frow lanes (hnewv==0 for !act)
            const float wpv = WPs[eo & 127];
            float sd[4], s1[4], s2[4];
#pragma unroll
            for (int j = 0; j < 4; ++j) {
                sd[j] = hnewv[j] * wpv;
                s1[j] = hnewv[j];
                s2[j] = hnewv[j] * hnewv[j];
            }
#pragma unroll
            for (int d = 1; d < 16; d <<= 1) {
#pragma unroll
                for (int j = 0; j < 4; ++j) {
                    sd[j] += __shfl_xor(sd[j], d);
                    s1[j] += __shfl_xor(s1[j], d);
                    s2[j] += __shfl_xor(s2[j], d);
                }
            }
            if (frow == 0 && fgrp < 2) {
                const int abase = ((t & 1) << 5) + fgrp * 16;
#pragma unroll
                for (int j = 0; j < 4; ++j) {
                    atomicAdd(&ACCs[abase + j * 4 + 0], sd[j]);
                    atomicAdd(&ACCs[abase + j * 4 + 1], s1[j]);
                    atomicAdd(&ACCs[abase + j * 4 + 2], s2[j]);
                }
            }
        }
        __syncthreads();

        // ===== phase C: cand+head MFMA, p/LN finalize, m update, head store =====
        {
            short8v ahw[NKC];
#pragma unroll
            for (int c = 0; c < NKC; ++c)
                ahw[c] = *(const short8v*)&Hwrow[c * 32 + fgrp * 8];
            float4v cc = (float4v){0.f, 0.f, 0.f, 0.f};
#pragma unroll
            for (int c = 0; c < NKC; ++c)
                cc = __builtin_amdgcn_mfma_f32_16x16x32_bf16(ahw[c], wmf[c], cc, 0, 0, 0);
#pragma unroll
            for (int j = 0; j < 4; ++j) candv[j] = cc[j];

            if (hdw) {
                float4v ad = (float4v){0.f, 0.f, 0.f, 0.f};
#pragma unroll
                for (int c = 0; c < NKC; ++c)
                    ad = __builtin_amdgcn_mfma_f32_16x16x32_bf16(ahw[c], hdf[c], ad, 0, 0, 0);
#pragma unroll
                for (int j = 0; j < 4; ++j) hdv[j] = ad[j];
            }

            const int abase = (t & 1) << 5;
            if (act) {
                const float bm = BMs[eo];
#pragma unroll
                for (int j = 0; j < 4; ++j) {
                    const int r = fgrp * 4 + j;
                    const float pv = sigmoid_f(ACCs[abase + r * 4 + 0] + bp);
                    const float cand = tanh_f(candv[j] + bm);
                    const float mold = bf2f(Ms[r * HSTR + eo]);
                    const float mnew = (1.0f - pv) * mold + pv * cand;
                    Ms[r * HSTR + eo] = f2bf(mnew);
                }
            }
            if (hdw && fgrp < 2 && vo < V_) {
                const float c1v = C1s[vo], c2v = C2Bs[vo];
#pragma unroll
                for (int j = 0; j < 4; ++j) {
                    const int r = fgrp * 4 + j;
                    const float s1v = ACCs[abase + r * 4 + 1];
                    const float s2v = ACCs[abase + r * 4 + 2];
                    const float mu = s1v * (1.0f / (float)E_);
                    const float var = s2v * (1.0f / (float)E_) - mu * mu;
                    const float rs = rsqrtf(var + 1e-5f);
                    const float lg = rs * (hdv[j] - mu * c1v) + c2v;
                    __builtin_nontemporal_store(
                        lg, &out[((size_t)(b0 + r) * T_ + t) * V_ + vo]);
                }
            }
        }
        __syncthreads();
    }
}

extern "C" void kernel_launch(void* const* d_in, const int* in_sizes, int n_in,
                              void* d_out, int out_size, void* d_ws, size_t ws_size,
                              hipStream_t stream) {
    const int* idx = (const int*)d_in[0];
    const float* tok = (const float*)d_in[1];
    const float* pos = (const float*)d_in[2];
    const float* w_ih = (const float*)d_in[3];
    const float* w_hh = (const float*)d_in[4];
    const float* b_ih = (const float*)d_in[5];
    const float* b_hh = (const float*)d_in[6];
    const float* w_p = (const float*)d_in[7];
    const float* b_p = (const float*)d_in[8];
    const float* w_m = (const float*)d_in[9];
    const float* b_m = (const float*)d_in[10];
    const float* ln_g = (const float*)d_in[11];
    const float* ln_b = (const float*)d_in[12];
    const float* w_head = (const float*)d_in[13];
    const float* b_head = (const float*)d_in[14];
    float* out = (float*)d_out;
    unsigned short* ws = (unsigned short*)d_ws;

    prep_weights<<<680, 256, 0, stream>>>(w_ih, w_hh, w_m, w_head, ln_g, ws);

    (void)hipFuncSetAttribute((const void*)gru_main,
                              hipFuncAttributeMaxDynamicSharedMemorySize,
                              SMEM_BYTES);
    gru_main<<<NB_, NT_, SMEM_BYTES, stream>>>(idx, tok, pos, b_ih, b_hh, w_p, b_p,
                                               b_m, ln_g, ln_b, w_head, b_head, ws, out);
}

// Round 16
// 887.185 us; speedup vs baseline: 1.1908x; 1.1908x over previous
//
#include <hip/hip_runtime.h>
#include <math.h>

// Problem constants
#define B_   2048
#define T_   256
#define E_   124
#define V_   65
#define E2_  248
#define E3_  372
#define R_   8               // batch rows per block (A-fragment rows 0-7; rows 8-15 zero)
#define NT_  512             // 8 waves
#define NB_  (B_ / R_)       // 256 blocks -> 1 per CU
#define NKC  4               // K chunks (124 padded to 128)
#define TCH  8               // timestep chunk for GX precompute

// ws offsets (unsigned shorts); frag block = 512 bf16 = 1KB — identical to R13/R14
#define WS_WX  0                    // 24*4*512 = 49152
#define WS_WM2 49152
#define WS_HH  98304
#define WS_WM  147456               // 8*4*512
#define WS_HD  163840               // 5*4*512 (W' = ln_g ∘ w_head)
#define WS_END 174080               // shorts = 348160 B

// LDS byte offsets (16B aligned); single-bf16 state — identical to R14
#define HSTR 136    // row stride (shorts), 124 real + pad (pad stays 0)
#define GXSTR 376
#define L_M   0         // 8*272 = 2176
#define L_HA  2176
#define L_HB  4352
#define L_ZR  6528      // 272 B zero row (A rows 8-15)
#define L_GX  6800      // [8][8][376] shorts = 48128 -> 54928
#define L_XE  54928     // [8][8][136] shorts = 17408 -> 72336
#define L_BRZ 72336     // 248 f
#define L_BIN 73328
#define L_BHN 73824
#define L_BM  74320
#define L_WP  74816
#define L_C1  75312     // 68 f
#define L_C2B 75584     // 68 f
#define L_P   75856     // 8 f
#define L_MU  75888
#define L_RS  75920
#define L_IDX 75952     // 8*256 int = 8192
#define SMEM_BYTES 84160

typedef __attribute__((ext_vector_type(8))) short short8v;
typedef __attribute__((ext_vector_type(4))) float float4v;

__device__ __forceinline__ unsigned short f2bf(float x) {
    unsigned u = __float_as_uint(x);
    unsigned r = (u + 0x7fffu + ((u >> 16) & 1u)) >> 16;
    return (unsigned short)r;
}
__device__ __forceinline__ float bf2f(unsigned short s) {
    return __uint_as_float(((unsigned)s) << 16);
}
__device__ __forceinline__ float sigmoid_f(float x) {
    return 1.0f / (1.0f + __expf(-x));
}
__device__ __forceinline__ float tanh_f(float x) {
    return 2.0f / (1.0f + __expf(-2.0f * x)) - 1.0f;
}

// identical to R13/R14 (validated)
__global__ void prep_weights(const float* __restrict__ w_ih,
                             const float* __restrict__ w_hh,
                             const float* __restrict__ w_m,
                             const float* __restrict__ w_head,
                             const float* __restrict__ ln_g,
                             unsigned short* __restrict__ ws) {
    for (int n = blockIdx.x * blockDim.x + threadIdx.x; n < WS_END;
         n += gridDim.x * blockDim.x) {
        const int r9 = n & 511;
        const int lane = r9 >> 3, j = r9 & 7;
        const int krel = (lane >> 4) * 8 + j;   // 0..31
        const int colrel = lane & 15;
        float w = 0.f;
        if (n < WS_WM2) {                       // WX: w_ih[:, 0:124]
            const int blk = n >> 9;
            const int c = blk & 3, tt = (blk >> 2) & 7, g = blk >> 5;
            const int k = c * 32 + krel, e = tt * 16 + colrel;
            if (k < E_ && e < E_) w = w_ih[(g * E_ + e) * E2_ + k];
        } else if (n < WS_HH) {                 // WM2: w_ih[:, 124:248]
            const int blk = (n - WS_WM2) >> 9;
            const int c = blk & 3, tt = (blk >> 2) & 7, g = blk >> 5;
            const int k = c * 32 + krel, e = tt * 16 + colrel;
            if (k < E_ && e < E_) w = w_ih[(g * E_ + e) * E2_ + E_ + k];
        } else if (n < WS_WM) {                 // HH: w_hh
            const int blk = (n - WS_HH) >> 9;
            const int c = blk & 3, tt = (blk >> 2) & 7, g = blk >> 5;
            const int k = c * 32 + krel, e = tt * 16 + colrel;
            if (k < E_ && e < E_) w = w_hh[(g * E_ + e) * E_ + k];
        } else if (n < WS_HD) {                 // WM: w_m (cand)
            const int blk = (n - WS_WM) >> 9;
            const int c = blk & 3, tt = blk >> 2;
            const int k = c * 32 + krel, e = tt * 16 + colrel;
            if (k < E_ && e < E_) w = w_m[e * E_ + k];
        } else {                                // HD: W' = ln_g ∘ w_head
            const int blk = (n - WS_HD) >> 9;
            const int c = blk & 3, tt = blk >> 2;
            const int k = c * 32 + krel, v = tt * 16 + colrel;
            if (k < E_ && v < V_) w = w_head[v * E_ + k] * ln_g[k];
        }
        ws[n] = f2bf(w);
    }
}

__global__ void __launch_bounds__(NT_, 2)
gru_main(const int* __restrict__ idx, const float* __restrict__ tok,
         const float* __restrict__ pos,
         const float* __restrict__ b_ih, const float* __restrict__ b_hh,
         const float* __restrict__ w_p, const float* __restrict__ b_p,
         const float* __restrict__ b_m,
         const float* __restrict__ ln_g, const float* __restrict__ ln_b,
         const float* __restrict__ w_head, const float* __restrict__ b_head,
         const unsigned short* __restrict__ ws, float* __restrict__ out) {
    extern __shared__ char smraw[];
    unsigned short* Ms = (unsigned short*)(smraw + L_M);
    unsigned short* ZRs = (unsigned short*)(smraw + L_ZR);
    unsigned short* GXs = (unsigned short*)(smraw + L_GX);
    unsigned short* XEs = (unsigned short*)(smraw + L_XE);
    float* BRZs = (float*)(smraw + L_BRZ);
    float* BINs = (float*)(smraw + L_BIN);
    float* BHNs = (float*)(smraw + L_BHN);
    float* BMs = (float*)(smraw + L_BM);
    float* WPs = (float*)(smraw + L_WP);
    float* C1s = (float*)(smraw + L_C1);
    float* C2Bs = (float*)(smraw + L_C2B);
    float* Ps = (float*)(smraw + L_P);
    float* MUs = (float*)(smraw + L_MU);
    float* RSs = (float*)(smraw + L_RS);
    int* IDXs = (int*)(smraw + L_IDX);

    const int tid = threadIdx.x;
    const int lane = tid & 63;
    const int wv = tid >> 6;
    const int b0 = blockIdx.x * R_;
    const int frow = lane & 15;       // A row / C col
    const int fgrp = lane >> 4;       // k-group / C row-group
    const int eo = wv * 16 + frow;    // owned e (gate/cand column)
    const bool act = (fgrp < 2) && (eo < E_);
    const bool hdw = (wv >= 2) && (wv < 7);   // head waves
    const int vo = (wv - 2) * 16 + frow;      // head output col

    // ---- one-time staging ----
    for (int i = tid; i < E2_; i += NT_) BRZs[i] = b_ih[i] + b_hh[i];
    for (int i = tid; i < E_; i += NT_) {
        BINs[i] = b_ih[E2_ + i];
        BHNs[i] = b_hh[E2_ + i];
        BMs[i] = b_m[i];
        WPs[i] = w_p[i];
    }
    for (int v = tid; v < V_; v += NT_) {       // LN-fold constants
        float s1 = 0.f, s2 = 0.f;
        for (int e = 0; e < E_; ++e) {
            const float w = w_head[v * E_ + e];
            s1 += ln_g[e] * w;
            s2 += ln_b[e] * w;
        }
        C1s[v] = s1;
        C2Bs[v] = s2 + b_head[v];
    }
    for (int i = tid; i < R_ * T_; i += NT_) IDXs[i] = idx[b0 * T_ + i];
    // zero state (M,HA,HB,ZR = 3400 shorts) and XE
    for (int i = tid; i < 3400; i += NT_) ((unsigned short*)smraw)[i] = 0;
    for (int i = tid; i < TCH * R_ * HSTR; i += NT_) XEs[i] = 0;
    const float bp = b_p[0];

    // ---- permanent register caches: 128 VGPR (within the 129-256 granule) ----
    short8v hhf[3][NKC], wm2f[3][NKC], wmf[NKC], hdf[NKC];
#pragma unroll
    for (int g = 0; g < 3; ++g)
#pragma unroll
        for (int c = 0; c < NKC; ++c) {
            hhf[g][c]  = *(const short8v*)&ws[WS_HH  + ((g * 8 + wv) * NKC + c) * 512 + lane * 8];
            wm2f[g][c] = *(const short8v*)&ws[WS_WM2 + ((g * 8 + wv) * NKC + c) * 512 + lane * 8];
        }
    {
        const int ht = hdw ? (wv - 2) : 0;
#pragma unroll
        for (int c = 0; c < NKC; ++c) {
            wmf[c] = *(const short8v*)&ws[WS_WM + (wv * NKC + c) * 512 + lane * 8];
            hdf[c] = *(const short8v*)&ws[WS_HD + (ht * NKC + c) * 512 + lane * 8];
        }
    }

    // per-lane A-operand rows (frow 0-7 = real state rows, 8-15 = zero row)
    const unsigned short* Mrow = (frow < 8) ? Ms + frow * HSTR : ZRs;
    const unsigned short* Xrow = (frow < 8) ? XEs + frow * HSTR : ZRs;
    const int xstep = (frow < 8) ? R_ * HSTR : 0;
    __syncthreads();

    float hnewv[4] = {0.f, 0.f, 0.f, 0.f};
    float candv[4] = {0.f, 0.f, 0.f, 0.f};
    float hdv[4] = {0.f, 0.f, 0.f, 0.f};

    for (int t = 0; t < T_; ++t) {
        unsigned short* Hw = (unsigned short*)(smraw + ((t & 1) ? L_HB : L_HA));
        const unsigned short* Hr = (const unsigned short*)(smraw + ((t & 1) ? L_HA : L_HB));
        const unsigned short* Hrow = (frow < 8) ? Hr + frow * HSTR : ZRs;
        const unsigned short* Hwrow = (frow < 8) ? (const unsigned short*)Hw + frow * HSTR : ZRs;

        // ===== chunk phase (every 8 steps): GX[t..t+7] = W_x @ x =====
        if ((t & 7) == 0) {
#pragma unroll
            for (int p = 0; p < 4; ++p) {
                const int i = tid + p * NT_;
                if (i < TCH * R_ * 31) {
                    const int mt = i / 248;
                    const int rem = i - mt * 248;
                    const int rr = rem / 31, q = rem - (rem / 31) * 31;
                    const int token = IDXs[rr * T_ + t + mt];
                    const int k = q * 4;
                    const float4 tv = *(const float4*)&tok[token * E_ + k];
                    const float4 pv = *(const float4*)&pos[(t + mt) * E_ + k];
#pragma unroll
                    for (int jj = 0; jj < 4; ++jj) {
                        const float x = ((const float*)&tv)[jj] + ((const float*)&pv)[jj];
                        XEs[(mt * R_ + rr) * HSTR + k + jj] = f2bf(x);
                    }
                }
            }
            __syncthreads();
#pragma unroll
            for (int g = 0; g < 3; ++g) {
                short8v bx[NKC];
#pragma unroll
                for (int c = 0; c < NKC; ++c)
                    bx[c] = *(const short8v*)&ws[WS_WX + ((g * 8 + wv) * NKC + c) * 512 + lane * 8];
                for (int mt = 0; mt < TCH; ++mt) {
                    float4v ax = (float4v){0.f, 0.f, 0.f, 0.f};
#pragma unroll
                    for (int c = 0; c < NKC; ++c) {
                        const short8v a = *(const short8v*)&Xrow[mt * xstep + c * 32 + fgrp * 8];
                        ax = __builtin_amdgcn_mfma_f32_16x16x32_bf16(a, bx[c], ax, 0, 0, 0);
                    }
                    if (act) {
#pragma unroll
                        for (int j = 0; j < 4; ++j)
                            GXs[(mt * R_ + fgrp * 4 + j) * GXSTR + g * E_ + eo] = f2bf(ax[j]);
                    }
                }
            }
            // GX consumed lane-locally (same lane wrote its own gate entries)
        }

        // ===== phase A: gi_m/gh MFMAs + in-register gates -> h_new =====
        {
            short8v am[NKC], ah[NKC];
#pragma unroll
            for (int c = 0; c < NKC; ++c) {
                am[c] = *(const short8v*)&Mrow[c * 32 + fgrp * 8];
                ah[c] = *(const short8v*)&Hrow[c * 32 + fgrp * 8];
            }
            float4v accm[3], acch[3];
#pragma unroll
            for (int g = 0; g < 3; ++g) {
                accm[g] = (float4v){0.f, 0.f, 0.f, 0.f};
                acch[g] = (float4v){0.f, 0.f, 0.f, 0.f};
            }
#pragma unroll
            for (int g = 0; g < 3; ++g)
#pragma unroll
                for (int c = 0; c < NKC; ++c) {
                    accm[g] = __builtin_amdgcn_mfma_f32_16x16x32_bf16(am[c], wm2f[g][c], accm[g], 0, 0, 0);
                    acch[g] = __builtin_amdgcn_mfma_f32_16x16x32_bf16(ah[c], hhf[g][c], acch[g], 0, 0, 0);
                }
            // rows 0-7 land directly in fgrp 0/1 lanes — no cross-lane combine
            if (act) {
                const float brz0 = BRZs[eo], brz1 = BRZs[E_ + eo];
                const float bin = BINs[eo], bhn = BHNs[eo];
                const int gxbase = ((t & 7) * R_ + fgrp * 4) * GXSTR;
#pragma unroll
                for (int j = 0; j < 4; ++j) {
                    const int r = fgrp * 4 + j;
                    const unsigned short* gxp = &GXs[gxbase + j * GXSTR];
                    const float rg = sigmoid_f(bf2f(gxp[eo]) + accm[0][j] + acch[0][j] + brz0);
                    const float z = sigmoid_f(bf2f(gxp[E_ + eo]) + accm[1][j] + acch[1][j] + brz1);
                    const float nn = tanh_f(bf2f(gxp[E2_ + eo]) + accm[2][j] + bin + rg * (acch[2][j] + bhn));
                    const float hold = bf2f(Hr[r * HSTR + eo]);
                    const float hv = (1.0f - z) * nn + z * hold;
                    hnewv[j] = hv;
                    Hw[r * HSTR + eo] = f2bf(hv);
                }
            }
        }
        __syncthreads();

        // ===== phase C: cand MFMA (all) + head MFMA (wv2-6) + wave-per-row p/LN =====
        {
            short8v ahw[NKC];
#pragma unroll
            for (int c = 0; c < NKC; ++c)
                ahw[c] = *(const short8v*)&Hwrow[c * 32 + fgrp * 8];
            float4v cc = (float4v){0.f, 0.f, 0.f, 0.f};
#pragma unroll
            for (int c = 0; c < NKC; ++c)
                cc = __builtin_amdgcn_mfma_f32_16x16x32_bf16(ahw[c], wmf[c], cc, 0, 0, 0);
#pragma unroll
            for (int j = 0; j < 4; ++j) candv[j] = cc[j];

            if (hdw) {   // head on h_t with LN-folded weights W'
                float4v ad = (float4v){0.f, 0.f, 0.f, 0.f};
#pragma unroll
                for (int c = 0; c < NKC; ++c)
                    ad = __builtin_amdgcn_mfma_f32_16x16x32_bf16(ahw[c], hdf[c], ad, 0, 0, 0);
#pragma unroll
                for (int j = 0; j < 4; ++j) hdv[j] = ad[j];
            }

            // wave wv reduces row wv: p-dot + LN stats over e (64-lane butterfly)
            {
                const float h0 = bf2f(Hw[wv * HSTR + lane]);
                const bool hi = (lane < E_ - 64);
                const float h1v = hi ? bf2f(Hw[wv * HSTR + 64 + lane]) : 0.f;
                float s = h0 * WPs[lane] + (hi ? h1v * WPs[64 + lane] : 0.f);
                float s1 = h0 + h1v;
                float s2 = h0 * h0 + h1v * h1v;
#pragma unroll
                for (int d = 1; d < 64; d <<= 1) {
                    s += __shfl_xor(s, d);
                    s1 += __shfl_xor(s1, d);
                    s2 += __shfl_xor(s2, d);
                }
                if (lane == 0) {
                    Ps[wv] = sigmoid_f(s + bp);
                    const float mu = s1 * (1.0f / (float)E_);
                    const float var = s2 * (1.0f / (float)E_) - mu * mu;
                    MUs[wv] = mu;
                    RSs[wv] = rsqrtf(var + 1e-5f);
                }
            }
        }
        __syncthreads();

        // ===== phase D: m update + head fixup/store =====
        if (act) {
            const float bm = BMs[eo];
#pragma unroll
            for (int j = 0; j < 4; ++j) {
                const int r = fgrp * 4 + j;
                const float pv = Ps[r];
                const float cand = tanh_f(candv[j] + bm);
                const float mold = bf2f(Ms[r * HSTR + eo]);
                const float mnew = (1.0f - pv) * mold + pv * cand;
                Ms[r * HSTR + eo] = f2bf(mnew);
            }
        }
        if (hdw && fgrp < 2 && vo < V_) {
            const float c1v = C1s[vo], c2v = C2Bs[vo];
#pragma unroll
            for (int j = 0; j < 4; ++j) {
                const int r = fgrp * 4 + j;
                const float lg = RSs[r] * (hdv[j] - MUs[r] * c1v) + c2v;
                __builtin_nontemporal_store(
                    lg, &out[((size_t)(b0 + r) * T_ + t) * V_ + vo]);
            }
        }
        __syncthreads();
    }
}

extern "C" void kernel_launch(void* const* d_in, const int* in_sizes, int n_in,
                              void* d_out, int out_size, void* d_ws, size_t ws_size,
                              hipStream_t stream) {
    const int* idx = (const int*)d_in[0];
    const float* tok = (const float*)d_in[1];
    const float* pos = (const float*)d_in[2];
    const float* w_ih = (const float*)d_in[3];
    const float* w_hh = (const float*)d_in[4];
    const float* b_ih = (const float*)d_in[5];
    const float* b_hh = (const float*)d_in[6];
    const float* w_p = (const float*)d_in[7];
    const float* b_p = (const float*)d_in[8];
    const float* w_m = (const float*)d_in[9];
    const float* b_m = (const float*)d_in[10];
    const float* ln_g = (const float*)d_in[11];
    const float* ln_b = (const float*)d_in[12];
    const float* w_head = (const float*)d_in[13];
    const float* b_head = (const float*)d_in[14];
    float* out = (float*)d_out;
    unsigned short* ws = (unsigned short*)d_ws;

    prep_weights<<<680, 256, 0, stream>>>(w_ih, w_hh, w_m, w_head, ln_g, ws);

    (void)hipFuncSetAttribute((const void*)gru_main,
                              hipFuncAttributeMaxDynamicSharedMemorySize,
                              SMEM_BYTES);
    gru_main<<<NB_, NT_, SMEM_BYTES, stream>>>(idx, tok, pos, b_ih, b_hh, w_p, b_p,
                                               b_m, ln_g, ln_b, w_head, b_head, ws, out);
}

// Round 17
// 846.951 us; speedup vs baseline: 1.2474x; 1.0475x over previous
//
#include <hip/hip_runtime.h>
#include <math.h>

// Problem constants
#define B_   2048
#define T_   256
#define E_   124
#define V_   65
#define E2_  248
#define R_   8               // batch rows per block (A rows 0-7; rows 8-15 zero)
#define NT_  512             // 8 waves
#define NB_  (B_ / R_)       // 256 blocks -> 1 per CU
#define NKC  4               // K chunks (124 padded to 128)
#define TCH  8               // timestep chunk for GX precompute

// ws offsets (unsigned shorts); identical to R13/R14/R16 (validated)
#define WS_WX  0
#define WS_WM2 49152
#define WS_HH  98304
#define WS_WM  147456
#define WS_HD  163840               // W' = ln_g ∘ w_head
#define WS_END 174080

// LDS byte offsets (16B aligned); single-bf16 state — identical to R14/R16
#define HSTR 136
#define GXSTR 376
#define L_M   0         // 2176
#define L_HA  2176
#define L_HB  4352
#define L_ZR  6528      // 272 B zero row
#define L_GX  6800      // 48128 -> 54928
#define L_XE  54928     // 17408 -> 72336
#define L_BRZ 72336     // 248 f
#define L_BIN 73328
#define L_BHN 73824
#define L_BM  74320
#define L_WP  74816
#define L_C1  75312     // 68 f
#define L_C2B 75584     // 68 f
#define L_IDX 75952     // 8192
#define SMEM_BYTES 84160

typedef __attribute__((ext_vector_type(8))) short short8v;
typedef __attribute__((ext_vector_type(4))) float float4v;

__device__ __forceinline__ unsigned short f2bf(float x) {
    unsigned u = __float_as_uint(x);
    unsigned r = (u + 0x7fffu + ((u >> 16) & 1u)) >> 16;
    return (unsigned short)r;
}
__device__ __forceinline__ float bf2f(unsigned short s) {
    return __uint_as_float(((unsigned)s) << 16);
}
__device__ __forceinline__ float sigmoid_f(float x) {
    return 1.0f / (1.0f + __expf(-x));
}
__device__ __forceinline__ float tanh_f(float x) {
    return 2.0f / (1.0f + __expf(-2.0f * x)) - 1.0f;
}

// identical to R13/R14/R16 (validated)
__global__ void prep_weights(const float* __restrict__ w_ih,
                             const float* __restrict__ w_hh,
                             const float* __restrict__ w_m,
                             const float* __restrict__ w_head,
                             const float* __restrict__ ln_g,
                             unsigned short* __restrict__ ws) {
    for (int n = blockIdx.x * blockDim.x + threadIdx.x; n < WS_END;
         n += gridDim.x * blockDim.x) {
        const int r9 = n & 511;
        const int lane = r9 >> 3, j = r9 & 7;
        const int krel = (lane >> 4) * 8 + j;   // 0..31
        const int colrel = lane & 15;
        float w = 0.f;
        if (n < WS_WM2) {                       // WX: w_ih[:, 0:124]
            const int blk = n >> 9;
            const int c = blk & 3, tt = (blk >> 2) & 7, g = blk >> 5;
            const int k = c * 32 + krel, e = tt * 16 + colrel;
            if (k < E_ && e < E_) w = w_ih[(g * E_ + e) * E2_ + k];
        } else if (n < WS_WM) {
            if (n < WS_HH) {                    // WM2: w_ih[:, 124:248]
                const int blk = (n - WS_WM2) >> 9;
                const int c = blk & 3, tt = (blk >> 2) & 7, g = blk >> 5;
                const int k = c * 32 + krel, e = tt * 16 + colrel;
                if (k < E_ && e < E_) w = w_ih[(g * E_ + e) * E2_ + E_ + k];
            } else {                            // HH: w_hh
                const int blk = (n - WS_HH) >> 9;
                const int c = blk & 3, tt = (blk >> 2) & 7, g = blk >> 5;
                const int k = c * 32 + krel, e = tt * 16 + colrel;
                if (k < E_ && e < E_) w = w_hh[(g * E_ + e) * E_ + k];
            }
        } else if (n < WS_HD) {                 // WM: w_m (cand)
            const int blk = (n - WS_WM) >> 9;
            const int c = blk & 3, tt = blk >> 2;
            const int k = c * 32 + krel, e = tt * 16 + colrel;
            if (k < E_ && e < E_) w = w_m[e * E_ + k];
        } else {                                // HD: W' = ln_g ∘ w_head
            const int blk = (n - WS_HD) >> 9;
            const int c = blk & 3, tt = blk >> 2;
            const int k = c * 32 + krel, v = tt * 16 + colrel;
            if (k < E_ && v < V_) w = w_head[v * E_ + k] * ln_g[k];
        }
        ws[n] = f2bf(w);
    }
}

__global__ void __launch_bounds__(NT_, 2)
gru_main(const int* __restrict__ idx, const float* __restrict__ tok,
         const float* __restrict__ pos,
         const float* __restrict__ b_ih, const float* __restrict__ b_hh,
         const float* __restrict__ w_p, const float* __restrict__ b_p,
         const float* __restrict__ b_m,
         const float* __restrict__ ln_g, const float* __restrict__ ln_b,
         const float* __restrict__ w_head, const float* __restrict__ b_head,
         const unsigned short* __restrict__ ws, float* __restrict__ out) {
    extern __shared__ char smraw[];
    unsigned short* Ms = (unsigned short*)(smraw + L_M);
    unsigned short* ZRs = (unsigned short*)(smraw + L_ZR);
    unsigned short* GXs = (unsigned short*)(smraw + L_GX);
    unsigned short* XEs = (unsigned short*)(smraw + L_XE);
    float* BRZs = (float*)(smraw + L_BRZ);
    float* BINs = (float*)(smraw + L_BIN);
    float* BHNs = (float*)(smraw + L_BHN);
    float* BMs = (float*)(smraw + L_BM);
    float* WPs = (float*)(smraw + L_WP);
    float* C1s = (float*)(smraw + L_C1);
    float* C2Bs = (float*)(smraw + L_C2B);
    int* IDXs = (int*)(smraw + L_IDX);

    const int tid = threadIdx.x;
    const int lane = tid & 63;
    const int wv = tid >> 6;
    const int b0 = blockIdx.x * R_;
    const int frow = lane & 15;       // A row / C col
    const int fgrp = lane >> 4;       // k-group / C row-group
    const int eo = wv * 16 + frow;    // owned e (gate/cand column)
    const bool act = (fgrp < 2) && (eo < E_);
    const bool hdw = (wv >= 2) && (wv < 7);   // head waves
    const int vo = (wv - 2) * 16 + frow;      // head output col

    // ---- one-time staging ----
    for (int i = tid; i < E2_; i += NT_) BRZs[i] = b_ih[i] + b_hh[i];
    for (int i = tid; i < E_; i += NT_) {
        BINs[i] = b_ih[E2_ + i];
        BHNs[i] = b_hh[E2_ + i];
        BMs[i] = b_m[i];
        WPs[i] = w_p[i];
    }
    for (int v = tid; v < V_; v += NT_) {       // LN-fold constants
        float s1 = 0.f, s2 = 0.f;
        for (int e = 0; e < E_; ++e) {
            const float w = w_head[v * E_ + e];
            s1 += ln_g[e] * w;
            s2 += ln_b[e] * w;
        }
        C1s[v] = s1;
        C2Bs[v] = s2 + b_head[v];
    }
    for (int i = tid; i < R_ * T_; i += NT_) IDXs[i] = idx[b0 * T_ + i];
    for (int i = tid; i < 3400; i += NT_) ((unsigned short*)smraw)[i] = 0;  // M,HA,HB,ZR
    for (int i = tid; i < TCH * R_ * HSTR; i += NT_) XEs[i] = 0;
    const float bp = b_p[0];

    // ---- permanent register caches ----
    short8v hhf[3][NKC], wm2f[3][NKC], wmf[NKC], hdf[NKC], wpf[NKC];
#pragma unroll
    for (int g = 0; g < 3; ++g)
#pragma unroll
        for (int c = 0; c < NKC; ++c) {
            hhf[g][c]  = *(const short8v*)&ws[WS_HH  + ((g * 8 + wv) * NKC + c) * 512 + lane * 8];
            wm2f[g][c] = *(const short8v*)&ws[WS_WM2 + ((g * 8 + wv) * NKC + c) * 512 + lane * 8];
        }
    {
        const int ht = hdw ? (wv - 2) : 0;
#pragma unroll
        for (int c = 0; c < NKC; ++c) {
            wmf[c] = *(const short8v*)&ws[WS_WM + (wv * NKC + c) * 512 + lane * 8];
            hdf[c] = *(const short8v*)&ws[WS_HD + (ht * NKC + c) * 512 + lane * 8];
        }
    }
    // stats B-frag: cols 0-7 = w_p[k], cols 8-15 = 1/E (k<124), else 0
#pragma unroll
    for (int c = 0; c < NKC; ++c) {
#pragma unroll
        for (int j = 0; j < 8; ++j) {
            const int k = c * 32 + fgrp * 8 + j;
            float v = 0.f;
            if (k < E_) v = (frow < 8) ? w_p[k] : (1.0f / (float)E_);
            wpf[c][j] = (short)f2bf(v);
        }
    }

    // per-lane A-operand rows (frow 0-7 = real state rows, 8-15 = zero row)
    const unsigned short* Mrow = (frow < 8) ? Ms + frow * HSTR : ZRs;
    const unsigned short* Xrow = (frow < 8) ? XEs + frow * HSTR : ZRs;
    const int xstep = (frow < 8) ? R_ * HSTR : 0;
    __syncthreads();

    float hnewv[4] = {0.f, 0.f, 0.f, 0.f};

    for (int t = 0; t < T_; ++t) {
        unsigned short* Hw = (unsigned short*)(smraw + ((t & 1) ? L_HB : L_HA));
        const unsigned short* Hr = (const unsigned short*)(smraw + ((t & 1) ? L_HA : L_HB));
        const unsigned short* Hrow = (frow < 8) ? Hr + frow * HSTR : ZRs;
        const unsigned short* Hwrow = (frow < 8) ? (const unsigned short*)Hw + frow * HSTR : ZRs;

        // ===== chunk phase (every 8 steps): GX[t..t+7] = W_x @ x =====
        if ((t & 7) == 0) {
#pragma unroll
            for (int p = 0; p < 4; ++p) {
                const int i = tid + p * NT_;
                if (i < TCH * R_ * 31) {
                    const int mt = i / 248;
                    const int rem = i - mt * 248;
                    const int rr = rem / 31, q = rem - (rem / 31) * 31;
                    const int token = IDXs[rr * T_ + t + mt];
                    const int k = q * 4;
                    const float4 tv = *(const float4*)&tok[token * E_ + k];
                    const float4 pv = *(const float4*)&pos[(t + mt) * E_ + k];
#pragma unroll
                    for (int jj = 0; jj < 4; ++jj) {
                        const float x = ((const float*)&tv)[jj] + ((const float*)&pv)[jj];
                        XEs[(mt * R_ + rr) * HSTR + k + jj] = f2bf(x);
                    }
                }
            }
            __syncthreads();
#pragma unroll
            for (int g = 0; g < 3; ++g) {
                short8v bx[NKC];
#pragma unroll
                for (int c = 0; c < NKC; ++c)
                    bx[c] = *(const short8v*)&ws[WS_WX + ((g * 8 + wv) * NKC + c) * 512 + lane * 8];
                for (int mt = 0; mt < TCH; ++mt) {
                    float4v ax = (float4v){0.f, 0.f, 0.f, 0.f};
#pragma unroll
                    for (int c = 0; c < NKC; ++c) {
                        const short8v a = *(const short8v*)&Xrow[mt * xstep + c * 32 + fgrp * 8];
                        ax = __builtin_amdgcn_mfma_f32_16x16x32_bf16(a, bx[c], ax, 0, 0, 0);
                    }
                    if (act) {
#pragma unroll
                        for (int j = 0; j < 4; ++j)
                            GXs[(mt * R_ + fgrp * 4 + j) * GXSTR + g * E_ + eo] = f2bf(ax[j]);
                    }
                }
            }
            // GX consumed lane-locally (same lane wrote its own gate entries)
        }

        // ===== phase A: gi_m/gh MFMAs + in-register gates -> h_new =====
        {
            short8v am[NKC], ah[NKC];
#pragma unroll
            for (int c = 0; c < NKC; ++c) {
                am[c] = *(const short8v*)&Mrow[c * 32 + fgrp * 8];
                ah[c] = *(const short8v*)&Hrow[c * 32 + fgrp * 8];
            }
            float4v accm[3], acch[3];
#pragma unroll
            for (int g = 0; g < 3; ++g) {
                accm[g] = (float4v){0.f, 0.f, 0.f, 0.f};
                acch[g] = (float4v){0.f, 0.f, 0.f, 0.f};
            }
#pragma unroll
            for (int g = 0; g < 3; ++g)
#pragma unroll
                for (int c = 0; c < NKC; ++c) {
                    accm[g] = __builtin_amdgcn_mfma_f32_16x16x32_bf16(am[c], wm2f[g][c], accm[g], 0, 0, 0);
                    acch[g] = __builtin_amdgcn_mfma_f32_16x16x32_bf16(ah[c], hhf[g][c], acch[g], 0, 0, 0);
                }
            if (act) {
                const float brz0 = BRZs[eo], brz1 = BRZs[E_ + eo];
                const float bin = BINs[eo], bhn = BHNs[eo];
                const int gxbase = ((t & 7) * R_ + fgrp * 4) * GXSTR;
#pragma unroll
                for (int j = 0; j < 4; ++j) {
                    const int r = fgrp * 4 + j;
                    const unsigned short* gxp = &GXs[gxbase + j * GXSTR];
                    const float rg = sigmoid_f(bf2f(gxp[eo]) + accm[0][j] + acch[0][j] + brz0);
                    const float z = sigmoid_f(bf2f(gxp[E_ + eo]) + accm[1][j] + acch[1][j] + brz1);
                    const float nn = tanh_f(bf2f(gxp[E2_ + eo]) + accm[2][j] + bin + rg * (acch[2][j] + bhn));
                    const float hold = bf2f(Hr[r * HSTR + eo]);
                    const float hv = (1.0f - z) * nn + z * hold;
                    hnewv[j] = hv;
                    Hw[r * HSTR + eo] = f2bf(hv);
                }
            }
        }
        __syncthreads();

        // ===== phase C: cand + head + MFMA-fused reductions + m update + store =====
        {
            short8v ahw[NKC];
#pragma unroll
            for (int c = 0; c < NKC; ++c)
                ahw[c] = *(const short8v*)&Hwrow[c * 32 + fgrp * 8];

            float4v cc = (float4v){0.f, 0.f, 0.f, 0.f};
            float4v pm = (float4v){0.f, 0.f, 0.f, 0.f};
            float4v gr = (float4v){0.f, 0.f, 0.f, 0.f};
#pragma unroll
            for (int c = 0; c < NKC; ++c) {
                cc = __builtin_amdgcn_mfma_f32_16x16x32_bf16(ahw[c], wmf[c], cc, 0, 0, 0);
                pm = __builtin_amdgcn_mfma_f32_16x16x32_bf16(ahw[c], wpf[c], pm, 0, 0, 0);
                gr = __builtin_amdgcn_mfma_f32_16x16x32_bf16(ahw[c], ahw[c], gr, 0, 0, 0);
            }
            float4v ad = (float4v){0.f, 0.f, 0.f, 0.f};
            if (hdw) {
#pragma unroll
                for (int c = 0; c < NKC; ++c)
                    ad = __builtin_amdgcn_mfma_f32_16x16x32_bf16(ahw[c], hdf[c], ad, 0, 0, 0);
            }

            // per-lane stats: pdot/mu via xor-8 swap; sumsq diag via bpermute
            float pvv[4], muv[4], rsv[4];
#pragma unroll
            for (int j = 0; j < 4; ++j) {
                const float other = __shfl_xor(pm[j], 8);
                const float pdot = (frow < 8) ? pm[j] : other;
                const float mu = (frow < 8) ? other : pm[j];
                const float s2 = __shfl(gr[j], 20 * fgrp + j);
                pvv[j] = sigmoid_f(pdot + bp);
                muv[j] = mu;
                const float var = s2 * (1.0f / (float)E_) - mu * mu;
                rsv[j] = rsqrtf(var + 1e-5f);
            }

            if (act) {
                const float bm = BMs[eo];
#pragma unroll
                for (int j = 0; j < 4; ++j) {
                    const int r = fgrp * 4 + j;
                    const float cand = tanh_f(cc[j] + bm);
                    const float mold = bf2f(Ms[r * HSTR + eo]);
                    const float mnew = (1.0f - pvv[j]) * mold + pvv[j] * cand;
                    Ms[r * HSTR + eo] = f2bf(mnew);
                }
            }
            if (hdw && fgrp < 2 && vo < V_) {
                const float c1v = C1s[vo], c2v = C2Bs[vo];
#pragma unroll
                for (int j = 0; j < 4; ++j) {
                    const int r = fgrp * 4 + j;
                    const float lg = rsv[j] * (ad[j] - muv[j] * c1v) + c2v;
                    __builtin_nontemporal_store(
                        lg, &out[((size_t)(b0 + r) * T_ + t) * V_ + vo]);
                }
            }
        }
        __syncthreads();
    }
}

extern "C" void kernel_launch(void* const* d_in, const int* in_sizes, int n_in,
                              void* d_out, int out_size, void* d_ws, size_t ws_size,
                              hipStream_t stream) {
    const int* idx = (const int*)d_in[0];
    const float* tok = (const float*)d_in[1];
    const float* pos = (const float*)d_in[2];
    const float* w_ih = (const float*)d_in[3];
    const float* w_hh = (const float*)d_in[4];
    const float* b_ih = (const float*)d_in[5];
    const float* b_hh = (const float*)d_in[6];
    const float* w_p = (const float*)d_in[7];
    const float* b_p = (const float*)d_in[8];
    const float* w_m = (const float*)d_in[9];
    const float* b_m = (const float*)d_in[10];
    const float* ln_g = (const float*)d_in[11];
    const float* ln_b = (const float*)d_in[12];
    const float* w_head = (const float*)d_in[13];
    const float* b_head = (const float*)d_in[14];
    float* out = (float*)d_out;
    unsigned short* ws = (unsigned short*)d_ws;

    prep_weights<<<680, 256, 0, stream>>>(w_ih, w_hh, w_m, w_head, ln_g, ws);

    (void)hipFuncSetAttribute((const void*)gru_main,
                              hipFuncAttributeMaxDynamicSharedMemorySize,
                              SMEM_BYTES);
    gru_main<<<NB_, NT_, SMEM_BYTES, stream>>>(idx, tok, pos, b_ih, b_hh, w_p, b_p,
                                               b_m, ln_g, ln_b, w_head, b_head, ws, out);
}

// Round 18
// 715.315 us; speedup vs baseline: 1.4769x; 1.1840x over previous
//
#include <hip/hip_runtime.h>
#include <math.h>

// Problem constants
#define B_   2048
#define T_   256
#define E_   124
#define V_   65
#define E2_  248
#define R_   8               // batch rows per block (A rows 0-7; rows 8-15 zero)
#define NT_  512             // 8 waves
#define NB_  (B_ / R_)       // 256 blocks -> 1 per CU
#define NKC  4               // K chunks (124 padded to 128)
#define TCH  8               // timestep chunk for GX precompute

// ws offsets (unsigned shorts); identical to R13..R17 (validated)
#define WS_WX  0
#define WS_WM2 49152
#define WS_HH  98304
#define WS_WM  147456
#define WS_HD  163840               // W' = ln_g ∘ w_head
#define WS_END 174080

// LDS byte offsets (16B aligned); single-bf16 state — identical to R14..R17
#define HSTR 136
#define GXSTR 376
#define L_M   0         // 2176
#define L_HA  2176
#define L_HB  4352
#define L_ZR  6528      // 272 B zero row
#define L_GX  6800      // 48128 -> 54928
#define L_XE  54928     // 17408 -> 72336
#define L_BRZ 72336     // 248 f
#define L_BIN 73328
#define L_BHN 73824
#define L_BM  74320
#define L_WP  74816
#define L_C1  75312     // 68 f
#define L_C2B 75584     // 68 f
#define L_IDX 75952     // 8192
#define SMEM_BYTES 84160

typedef __attribute__((ext_vector_type(8))) short short8v;
typedef __attribute__((ext_vector_type(4))) float float4v;

__device__ __forceinline__ unsigned short f2bf(float x) {
    unsigned u = __float_as_uint(x);
    unsigned r = (u + 0x7fffu + ((u >> 16) & 1u)) >> 16;
    return (unsigned short)r;
}
__device__ __forceinline__ float bf2f(unsigned short s) {
    return __uint_as_float(((unsigned)s) << 16);
}
__device__ __forceinline__ float sigmoid_f(float x) {
    return 1.0f / (1.0f + __expf(-x));
}
__device__ __forceinline__ float tanh_f(float x) {
    return 2.0f / (1.0f + __expf(-2.0f * x)) - 1.0f;
}

// identical to R13..R17 (validated)
__global__ void prep_weights(const float* __restrict__ w_ih,
                             const float* __restrict__ w_hh,
                             const float* __restrict__ w_m,
                             const float* __restrict__ w_head,
                             const float* __restrict__ ln_g,
                             unsigned short* __restrict__ ws) {
    for (int n = blockIdx.x * blockDim.x + threadIdx.x; n < WS_END;
         n += gridDim.x * blockDim.x) {
        const int r9 = n & 511;
        const int lane = r9 >> 3, j = r9 & 7;
        const int krel = (lane >> 4) * 8 + j;   // 0..31
        const int colrel = lane & 15;
        float w = 0.f;
        if (n < WS_WM2) {                       // WX: w_ih[:, 0:124]
            const int blk = n >> 9;
            const int c = blk & 3, tt = (blk >> 2) & 7, g = blk >> 5;
            const int k = c * 32 + krel, e = tt * 16 + colrel;
            if (k < E_ && e < E_) w = w_ih[(g * E_ + e) * E2_ + k];
        } else if (n < WS_WM) {
            if (n < WS_HH) {                    // WM2: w_ih[:, 124:248]
                const int blk = (n - WS_WM2) >> 9;
                const int c = blk & 3, tt = (blk >> 2) & 7, g = blk >> 5;
                const int k = c * 32 + krel, e = tt * 16 + colrel;
                if (k < E_ && e < E_) w = w_ih[(g * E_ + e) * E2_ + E_ + k];
            } else {                            // HH: w_hh
                const int blk = (n - WS_HH) >> 9;
                const int c = blk & 3, tt = (blk >> 2) & 7, g = blk >> 5;
                const int k = c * 32 + krel, e = tt * 16 + colrel;
                if (k < E_ && e < E_) w = w_hh[(g * E_ + e) * E_ + k];
            }
        } else if (n < WS_HD) {                 // WM: w_m (cand)
            const int blk = (n - WS_WM) >> 9;
            const int c = blk & 3, tt = blk >> 2;
            const int k = c * 32 + krel, e = tt * 16 + colrel;
            if (k < E_ && e < E_) w = w_m[e * E_ + k];
        } else {                                // HD: W' = ln_g ∘ w_head
            const int blk = (n - WS_HD) >> 9;
            const int c = blk & 3, tt = blk >> 2;
            const int k = c * 32 + krel, v = tt * 16 + colrel;
            if (k < E_ && v < V_) w = w_head[v * E_ + k] * ln_g[k];
        }
        ws[n] = f2bf(w);
    }
}

__global__ void __launch_bounds__(NT_, 2)
gru_main(const int* __restrict__ idx, const float* __restrict__ tok,
         const float* __restrict__ pos,
         const float* __restrict__ b_ih, const float* __restrict__ b_hh,
         const float* __restrict__ w_p, const float* __restrict__ b_p,
         const float* __restrict__ b_m,
         const float* __restrict__ ln_g, const float* __restrict__ ln_b,
         const float* __restrict__ w_head, const float* __restrict__ b_head,
         const unsigned short* __restrict__ ws, float* __restrict__ out) {
    extern __shared__ char smraw[];
    unsigned short* Ms = (unsigned short*)(smraw + L_M);
    unsigned short* ZRs = (unsigned short*)(smraw + L_ZR);
    unsigned short* GXs = (unsigned short*)(smraw + L_GX);
    unsigned short* XEs = (unsigned short*)(smraw + L_XE);
    float* BRZs = (float*)(smraw + L_BRZ);
    float* BINs = (float*)(smraw + L_BIN);
    float* BHNs = (float*)(smraw + L_BHN);
    float* BMs = (float*)(smraw + L_BM);
    float* WPs = (float*)(smraw + L_WP);
    float* C1s = (float*)(smraw + L_C1);
    float* C2Bs = (float*)(smraw + L_C2B);
    int* IDXs = (int*)(smraw + L_IDX);

    const int tid = threadIdx.x;
    const int lane = tid & 63;
    const int wv = tid >> 6;
    const int b0 = blockIdx.x * R_;
    const int frow = lane & 15;       // A row / C col
    const int fgrp = lane >> 4;       // k-group / C row-group
    const int eo = wv * 16 + frow;    // owned e (gate/cand column)
    const bool eon = (eo < E_);
    const bool actx = (fgrp < 2) && eon;        // chunk-phase GX writers
    const bool hdw = (wv >= 2) && (wv < 7);     // head waves
    const int vo = (wv - 2) * 16 + frow;        // head output col
    // lane-spread row base: fgrp0->{0,1} fgrp1->{4,5} fgrp2->{2,3} fgrp3->{6,7}
    const int rb = (fgrp < 2) ? fgrp * 4 : (fgrp - 2) * 4 + 2;

    // ---- one-time staging ----
    for (int i = tid; i < E2_; i += NT_) BRZs[i] = b_ih[i] + b_hh[i];
    for (int i = tid; i < E_; i += NT_) {
        BINs[i] = b_ih[E2_ + i];
        BHNs[i] = b_hh[E2_ + i];
        BMs[i] = b_m[i];
        WPs[i] = w_p[i];
    }
    for (int v = tid; v < V_; v += NT_) {       // LN-fold constants
        float s1 = 0.f, s2 = 0.f;
        for (int e = 0; e < E_; ++e) {
            const float w = w_head[v * E_ + e];
            s1 += ln_g[e] * w;
            s2 += ln_b[e] * w;
        }
        C1s[v] = s1;
        C2Bs[v] = s2 + b_head[v];
    }
    for (int i = tid; i < R_ * T_; i += NT_) IDXs[i] = idx[b0 * T_ + i];
    for (int i = tid; i < 3400; i += NT_) ((unsigned short*)smraw)[i] = 0;  // M,HA,HB,ZR
    for (int i = tid; i < TCH * R_ * HSTR; i += NT_) XEs[i] = 0;
    const float bp = b_p[0];

    // ---- permanent register caches ----
    short8v hhf[3][NKC], wm2f[3][NKC], wmf[NKC], hdf[NKC], wpf[NKC];
#pragma unroll
    for (int g = 0; g < 3; ++g)
#pragma unroll
        for (int c = 0; c < NKC; ++c) {
            hhf[g][c]  = *(const short8v*)&ws[WS_HH  + ((g * 8 + wv) * NKC + c) * 512 + lane * 8];
            wm2f[g][c] = *(const short8v*)&ws[WS_WM2 + ((g * 8 + wv) * NKC + c) * 512 + lane * 8];
        }
    {
        const int ht = hdw ? (wv - 2) : 0;
#pragma unroll
        for (int c = 0; c < NKC; ++c) {
            wmf[c] = *(const short8v*)&ws[WS_WM + (wv * NKC + c) * 512 + lane * 8];
            hdf[c] = *(const short8v*)&ws[WS_HD + (ht * NKC + c) * 512 + lane * 8];
        }
    }
    // stats B-frag: cols 0-7 = w_p[k], cols 8-15 = 1/E (k<124), else 0
#pragma unroll
    for (int c = 0; c < NKC; ++c) {
#pragma unroll
        for (int j = 0; j < 8; ++j) {
            const int k = c * 32 + fgrp * 8 + j;
            float v = 0.f;
            if (k < E_) v = (frow < 8) ? w_p[k] : (1.0f / (float)E_);
            wpf[c][j] = (short)f2bf(v);
        }
    }

    // per-lane A-operand rows (frow 0-7 = real state rows, 8-15 = zero row)
    const unsigned short* Mrow = (frow < 8) ? Ms + frow * HSTR : ZRs;
    const unsigned short* Xrow = (frow < 8) ? XEs + frow * HSTR : ZRs;
    const int xstep = (frow < 8) ? R_ * HSTR : 0;
    __syncthreads();

    for (int t = 0; t < T_; ++t) {
        unsigned short* Hw = (unsigned short*)(smraw + ((t & 1) ? L_HB : L_HA));
        const unsigned short* Hr = (const unsigned short*)(smraw + ((t & 1) ? L_HA : L_HB));
        const unsigned short* Hrow = (frow < 8) ? Hr + frow * HSTR : ZRs;
        const unsigned short* Hwrow = (frow < 8) ? (const unsigned short*)Hw + frow * HSTR : ZRs;

        // ===== chunk phase (every 8 steps): GX[t..t+7] = W_x @ x =====
        if ((t & 7) == 0) {
#pragma unroll
            for (int p = 0; p < 4; ++p) {
                const int i = tid + p * NT_;
                if (i < TCH * R_ * 31) {
                    const int mt = i / 248;
                    const int rem = i - mt * 248;
                    const int rr = rem / 31, q = rem - (rem / 31) * 31;
                    const int token = IDXs[rr * T_ + t + mt];
                    const int k = q * 4;
                    const float4 tv = *(const float4*)&tok[token * E_ + k];
                    const float4 pv = *(const float4*)&pos[(t + mt) * E_ + k];
#pragma unroll
                    for (int jj = 0; jj < 4; ++jj) {
                        const float x = ((const float*)&tv)[jj] + ((const float*)&pv)[jj];
                        XEs[(mt * R_ + rr) * HSTR + k + jj] = f2bf(x);
                    }
                }
            }
            __syncthreads();
#pragma unroll
            for (int g = 0; g < 3; ++g) {
                short8v bx[NKC];
#pragma unroll
                for (int c = 0; c < NKC; ++c)
                    bx[c] = *(const short8v*)&ws[WS_WX + ((g * 8 + wv) * NKC + c) * 512 + lane * 8];
                for (int mt = 0; mt < TCH; ++mt) {
                    float4v ax = (float4v){0.f, 0.f, 0.f, 0.f};
#pragma unroll
                    for (int c = 0; c < NKC; ++c) {
                        const short8v a = *(const short8v*)&Xrow[mt * xstep + c * 32 + fgrp * 8];
                        ax = __builtin_amdgcn_mfma_f32_16x16x32_bf16(a, bx[c], ax, 0, 0, 0);
                    }
                    if (actx) {
#pragma unroll
                        for (int j = 0; j < 4; ++j)
                            GXs[(mt * R_ + fgrp * 4 + j) * GXSTR + g * E_ + eo] = f2bf(ax[j]);
                    }
                }
            }
            // GX consumed lane-locally within the same fgrp-pair columns
        }

        // ===== phase A: gi_m/gh MFMAs + lane-spread gates -> h_new =====
        {
            short8v am[NKC], ah[NKC];
#pragma unroll
            for (int c = 0; c < NKC; ++c) {
                am[c] = *(const short8v*)&Mrow[c * 32 + fgrp * 8];
                ah[c] = *(const short8v*)&Hrow[c * 32 + fgrp * 8];
            }
            float4v accm[3], acch[3];
#pragma unroll
            for (int g = 0; g < 3; ++g) {
                accm[g] = (float4v){0.f, 0.f, 0.f, 0.f};
                acch[g] = (float4v){0.f, 0.f, 0.f, 0.f};
            }
#pragma unroll
            for (int g = 0; g < 3; ++g)
#pragma unroll
                for (int c = 0; c < NKC; ++c) {
                    accm[g] = __builtin_amdgcn_mfma_f32_16x16x32_bf16(am[c], wm2f[g][c], accm[g], 0, 0, 0);
                    acch[g] = __builtin_amdgcn_mfma_f32_16x16x32_bf16(ah[c], hhf[g][c], acch[g], 0, 0, 0);
                }
            // spread: fgrp2/3 receive partner's j=2,3 accumulators (xor-32)
            float am2[3][2], ah2[3][2];
#pragma unroll
            for (int g = 0; g < 3; ++g) {
                const float tm2 = __shfl_xor(accm[g][2], 32);
                const float tm3 = __shfl_xor(accm[g][3], 32);
                const float th2 = __shfl_xor(acch[g][2], 32);
                const float th3 = __shfl_xor(acch[g][3], 32);
                am2[g][0] = (fgrp < 2) ? accm[g][0] : tm2;
                am2[g][1] = (fgrp < 2) ? accm[g][1] : tm3;
                ah2[g][0] = (fgrp < 2) ? acch[g][0] : th2;
                ah2[g][1] = (fgrp < 2) ? acch[g][1] : th3;
            }
            if (eon) {
                const float brz0 = BRZs[eo], brz1 = BRZs[E_ + eo];
                const float bin = BINs[eo], bhn = BHNs[eo];
#pragma unroll
                for (int jj = 0; jj < 2; ++jj) {
                    const int r = rb + jj;
                    const unsigned short* gxp = &GXs[((t & 7) * R_ + r) * GXSTR];
                    const float rg = sigmoid_f(bf2f(gxp[eo]) + am2[0][jj] + ah2[0][jj] + brz0);
                    const float z = sigmoid_f(bf2f(gxp[E_ + eo]) + am2[1][jj] + ah2[1][jj] + brz1);
                    const float nn = tanh_f(bf2f(gxp[E2_ + eo]) + am2[2][jj] + bin + rg * (ah2[2][jj] + bhn));
                    const float hold = bf2f(Hr[r * HSTR + eo]);
                    const float hv = (1.0f - z) * nn + z * hold;
                    Hw[r * HSTR + eo] = f2bf(hv);
                }
            }
        }
        __syncthreads();

        // ===== phase C: cand+head+stats MFMAs, lane-spread finalize/store =====
        {
            short8v ahw[NKC];
#pragma unroll
            for (int c = 0; c < NKC; ++c)
                ahw[c] = *(const short8v*)&Hwrow[c * 32 + fgrp * 8];

            float4v cc = (float4v){0.f, 0.f, 0.f, 0.f};
            float4v pm = (float4v){0.f, 0.f, 0.f, 0.f};
            float4v gr = (float4v){0.f, 0.f, 0.f, 0.f};
#pragma unroll
            for (int c = 0; c < NKC; ++c) {
                cc = __builtin_amdgcn_mfma_f32_16x16x32_bf16(ahw[c], wmf[c], cc, 0, 0, 0);
                pm = __builtin_amdgcn_mfma_f32_16x16x32_bf16(ahw[c], wpf[c], pm, 0, 0, 0);
                gr = __builtin_amdgcn_mfma_f32_16x16x32_bf16(ahw[c], ahw[c], gr, 0, 0, 0);
            }
            float4v ad = (float4v){0.f, 0.f, 0.f, 0.f};
            if (hdw) {
#pragma unroll
                for (int c = 0; c < NKC; ++c)
                    ad = __builtin_amdgcn_mfma_f32_16x16x32_bf16(ahw[c], hdf[c], ad, 0, 0, 0);
            }

            // spread regs j=2,3 to fgrp2/3 partners
            const float tc2 = __shfl_xor(cc[2], 32), tc3 = __shfl_xor(cc[3], 32);
            const float tp2 = __shfl_xor(pm[2], 32), tp3 = __shfl_xor(pm[3], 32);
            const float ta2 = __shfl_xor(ad[2], 32), ta3 = __shfl_xor(ad[3], 32);
            float ccl[2], pml[2], adl[2], s2l[2];
            ccl[0] = (fgrp < 2) ? cc[0] : tc2;
            ccl[1] = (fgrp < 2) ? cc[1] : tc3;
            pml[0] = (fgrp < 2) ? pm[0] : tp2;
            pml[1] = (fgrp < 2) ? pm[1] : tp3;
            adl[0] = (fgrp < 2) ? ad[0] : ta2;
            adl[1] = (fgrp < 2) ? ad[1] : ta3;
            {   // Gram diag for rows rb, rb+1
                const float d0a = __shfl(gr[0], 20 * (fgrp & 1) + 0);
                const float d1a = __shfl(gr[1], 20 * (fgrp & 1) + 1);
                const float d0b = __shfl(gr[2], 20 * (fgrp & 1) + 2);
                const float d1b = __shfl(gr[3], 20 * (fgrp & 1) + 3);
                s2l[0] = (fgrp < 2) ? d0a : d0b;
                s2l[1] = (fgrp < 2) ? d1a : d1b;
            }

            // finalize per-row stats; m update; head store — 2 rows/lane, all lanes
            const float bm = BMs[eon ? eo : 0];
            const float c1v = C1s[(hdw && vo < V_) ? vo : 0];
            const float c2v = C2Bs[(hdw && vo < V_) ? vo : 0];
#pragma unroll
            for (int jj = 0; jj < 2; ++jj) {
                const int r = rb + jj;
                const float other = __shfl_xor(pml[jj], 8);
                const float pdot = (frow < 8) ? pml[jj] : other;
                const float mu = (frow < 8) ? other : pml[jj];
                const float pv = sigmoid_f(pdot + bp);
                const float var = s2l[jj] * (1.0f / (float)E_) - mu * mu;
                const float rs = rsqrtf(var + 1e-5f);
                if (eon) {
                    const float cand = tanh_f(ccl[jj] + bm);
                    const float mold = bf2f(Ms[r * HSTR + eo]);
                    Ms[r * HSTR + eo] = f2bf((1.0f - pv) * mold + pv * cand);
                }
                if (hdw && vo < V_) {
                    const float lg = rs * (adl[jj] - mu * c1v) + c2v;
                    __builtin_nontemporal_store(
                        lg, &out[((size_t)(b0 + r) * T_ + t) * V_ + vo]);
                }
            }
        }
        __syncthreads();
    }
}

extern "C" void kernel_launch(void* const* d_in, const int* in_sizes, int n_in,
                              void* d_out, int out_size, void* d_ws, size_t ws_size,
                              hipStream_t stream) {
    const int* idx = (const int*)d_in[0];
    const float* tok = (const float*)d_in[1];
    const float* pos = (const float*)d_in[2];
    const float* w_ih = (const float*)d_in[3];
    const float* w_hh = (const float*)d_in[4];
    const float* b_ih = (const float*)d_in[5];
    const float* b_hh = (const float*)d_in[6];
    const float* w_p = (const float*)d_in[7];
    const float* b_p = (const float*)d_in[8];
    const float* w_m = (const float*)d_in[9];
    const float* b_m = (const float*)d_in[10];
    const float* ln_g = (const float*)d_in[11];
    const float* ln_b = (const float*)d_in[12];
    const float* w_head = (const float*)d_in[13];
    const float* b_head = (const float*)d_in[14];
    float* out = (float*)d_out;
    unsigned short* ws = (unsigned short*)d_ws;

    prep_weights<<<680, 256, 0, stream>>>(w_ih, w_hh, w_m, w_head, ln_g, ws);

    (void)hipFuncSetAttribute((const void*)gru_main,
                              hipFuncAttributeMaxDynamicSharedMemorySize,
                              SMEM_BYTES);
    gru_main<<<NB_, NT_, SMEM_BYTES, stream>>>(idx, tok, pos, b_ih, b_hh, w_p, b_p,
                                               b_m, ln_g, ln_b, w_head, b_head, ws, out);
}

// Round 19
// 687.160 us; speedup vs baseline: 1.5374x; 1.0410x over previous
//
#include <hip/hip_runtime.h>
#include <math.h>

// Problem constants
#define B_   2048
#define T_   256
#define E_   124
#define V_   65
#define E2_  248
#define R_   8               // batch rows per block (A rows 0-7; rows 8-15 zero)
#define NT_  512             // 8 waves
#define NB_  (B_ / R_)       // 256 blocks -> 1 per CU
#define NKC  4               // K chunks (124 padded to 128)
#define TCH  8               // timestep chunk for GX precompute

// ws offsets (unsigned shorts); identical to R13..R18 (validated)
#define WS_WX  0
#define WS_WM2 49152
#define WS_HH  98304
#define WS_WM  147456
#define WS_HD  163840               // W' = ln_g ∘ w_head
#define WS_END 174080

// LDS byte offsets (16B aligned); single-bf16 state — identical to R14..R18
#define HSTR 136
#define GXSTR 376
#define L_M   0         // 2176
#define L_HA  2176
#define L_HB  4352
#define L_ZR  6528      // 272 B zero row
#define L_GX  6800      // 48128 -> 54928
#define L_XE  54928     // 17408 -> 72336
#define L_BRZ 72336     // 248 f
#define L_BIN 73328
#define L_BHN 73824
#define L_BM  74320
#define L_WP  74816
#define L_C1  75312     // 68 f
#define L_C2B 75584     // 68 f
#define L_IDX 75952     // 8192
#define SMEM_BYTES 84160

typedef __attribute__((ext_vector_type(8))) short short8v;
typedef __attribute__((ext_vector_type(4))) float float4v;

__device__ __forceinline__ unsigned short f2bf(float x) {
    unsigned u = __float_as_uint(x);
    unsigned r = (u + 0x7fffu + ((u >> 16) & 1u)) >> 16;
    return (unsigned short)r;
}
__device__ __forceinline__ float bf2f(unsigned short s) {
    return __uint_as_float(((unsigned)s) << 16);
}
__device__ __forceinline__ float sigmoid_f(float x) {
    return 1.0f / (1.0f + __expf(-x));
}
__device__ __forceinline__ float tanh_f(float x) {
    return 2.0f / (1.0f + __expf(-2.0f * x)) - 1.0f;
}

// identical to R13..R18 (validated)
__global__ void prep_weights(const float* __restrict__ w_ih,
                             const float* __restrict__ w_hh,
                             const float* __restrict__ w_m,
                             const float* __restrict__ w_head,
                             const float* __restrict__ ln_g,
                             unsigned short* __restrict__ ws) {
    for (int n = blockIdx.x * blockDim.x + threadIdx.x; n < WS_END;
         n += gridDim.x * blockDim.x) {
        const int r9 = n & 511;
        const int lane = r9 >> 3, j = r9 & 7;
        const int krel = (lane >> 4) * 8 + j;   // 0..31
        const int colrel = lane & 15;
        float w = 0.f;
        if (n < WS_WM2) {                       // WX: w_ih[:, 0:124]
            const int blk = n >> 9;
            const int c = blk & 3, tt = (blk >> 2) & 7, g = blk >> 5;
            const int k = c * 32 + krel, e = tt * 16 + colrel;
            if (k < E_ && e < E_) w = w_ih[(g * E_ + e) * E2_ + k];
        } else if (n < WS_WM) {
            if (n < WS_HH) {                    // WM2: w_ih[:, 124:248]
                const int blk = (n - WS_WM2) >> 9;
                const int c = blk & 3, tt = (blk >> 2) & 7, g = blk >> 5;
                const int k = c * 32 + krel, e = tt * 16 + colrel;
                if (k < E_ && e < E_) w = w_ih[(g * E_ + e) * E2_ + E_ + k];
            } else {                            // HH: w_hh
                const int blk = (n - WS_HH) >> 9;
                const int c = blk & 3, tt = (blk >> 2) & 7, g = blk >> 5;
                const int k = c * 32 + krel, e = tt * 16 + colrel;
                if (k < E_ && e < E_) w = w_hh[(g * E_ + e) * E_ + k];
            }
        } else if (n < WS_HD) {                 // WM: w_m (cand)
            const int blk = (n - WS_WM) >> 9;
            const int c = blk & 3, tt = blk >> 2;
            const int k = c * 32 + krel, e = tt * 16 + colrel;
            if (k < E_ && e < E_) w = w_m[e * E_ + k];
        } else {                                // HD: W' = ln_g ∘ w_head
            const int blk = (n - WS_HD) >> 9;
            const int c = blk & 3, tt = blk >> 2;
            const int k = c * 32 + krel, v = tt * 16 + colrel;
            if (k < E_ && v < V_) w = w_head[v * E_ + k] * ln_g[k];
        }
        ws[n] = f2bf(w);
    }
}

__global__ void __launch_bounds__(NT_, 2)
gru_main(const int* __restrict__ idx, const float* __restrict__ tok,
         const float* __restrict__ pos,
         const float* __restrict__ b_ih, const float* __restrict__ b_hh,
         const float* __restrict__ w_p, const float* __restrict__ b_p,
         const float* __restrict__ b_m,
         const float* __restrict__ ln_g, const float* __restrict__ ln_b,
         const float* __restrict__ w_head, const float* __restrict__ b_head,
         const unsigned short* __restrict__ ws, float* __restrict__ out) {
    extern __shared__ char smraw[];
    unsigned short* Ms = (unsigned short*)(smraw + L_M);
    unsigned short* ZRs = (unsigned short*)(smraw + L_ZR);
    unsigned short* GXs = (unsigned short*)(smraw + L_GX);
    unsigned short* XEs = (unsigned short*)(smraw + L_XE);
    float* BRZs = (float*)(smraw + L_BRZ);
    float* BINs = (float*)(smraw + L_BIN);
    float* BHNs = (float*)(smraw + L_BHN);
    float* BMs = (float*)(smraw + L_BM);
    float* WPs = (float*)(smraw + L_WP);
    float* C1s = (float*)(smraw + L_C1);
    float* C2Bs = (float*)(smraw + L_C2B);
    int* IDXs = (int*)(smraw + L_IDX);

    const int tid = threadIdx.x;
    const int lane = tid & 63;
    const int wv = tid >> 6;
    const int b0 = blockIdx.x * R_;
    const int frow = lane & 15;       // A row / C col
    const int fgrp = lane >> 4;       // k-group / C row-group
    const int eo = wv * 16 + frow;    // owned e (gate/cand column)
    const bool eon = (eo < E_);
    const bool actx = (fgrp < 2) && eon;        // chunk-phase GX writers
    const bool hdw = (wv >= 2) && (wv < 7);     // head waves
    const int vo = (wv - 2) * 16 + frow;        // head output col
    // lane-spread row base: fgrp0->{0,1} fgrp1->{4,5} fgrp2->{2,3} fgrp3->{6,7}
    const int rb = (fgrp < 2) ? fgrp * 4 : (fgrp - 2) * 4 + 2;

    // ---- one-time staging ----
    for (int i = tid; i < E2_; i += NT_) BRZs[i] = b_ih[i] + b_hh[i];
    for (int i = tid; i < E_; i += NT_) {
        BINs[i] = b_ih[E2_ + i];
        BHNs[i] = b_hh[E2_ + i];
        BMs[i] = b_m[i];
        WPs[i] = w_p[i];
    }
    for (int v = tid; v < V_; v += NT_) {       // LN-fold constants
        float s1 = 0.f, s2 = 0.f;
        for (int e = 0; e < E_; ++e) {
            const float w = w_head[v * E_ + e];
            s1 += ln_g[e] * w;
            s2 += ln_b[e] * w;
        }
        C1s[v] = s1;
        C2Bs[v] = s2 + b_head[v];
    }
    for (int i = tid; i < R_ * T_; i += NT_) IDXs[i] = idx[b0 * T_ + i];
    for (int i = tid; i < 3400; i += NT_) ((unsigned short*)smraw)[i] = 0;  // M,HA,HB,ZR
    for (int i = tid; i < TCH * R_ * HSTR; i += NT_) XEs[i] = 0;
    const float bp = b_p[0];

    // ---- permanent register caches ----
    short8v hhf[3][NKC], wm2f[3][NKC], wmf[NKC], hdf[NKC], wpf[NKC];
#pragma unroll
    for (int g = 0; g < 3; ++g)
#pragma unroll
        for (int c = 0; c < NKC; ++c) {
            hhf[g][c]  = *(const short8v*)&ws[WS_HH  + ((g * 8 + wv) * NKC + c) * 512 + lane * 8];
            wm2f[g][c] = *(const short8v*)&ws[WS_WM2 + ((g * 8 + wv) * NKC + c) * 512 + lane * 8];
        }
    {
        const int ht = hdw ? (wv - 2) : 0;
#pragma unroll
        for (int c = 0; c < NKC; ++c) {
            wmf[c] = *(const short8v*)&ws[WS_WM + (wv * NKC + c) * 512 + lane * 8];
            hdf[c] = *(const short8v*)&ws[WS_HD + (ht * NKC + c) * 512 + lane * 8];
        }
    }
    // stats B-frag: cols 0-7 = w_p[k], cols 8-15 = 1/E (k<124), else 0
#pragma unroll
    for (int c = 0; c < NKC; ++c) {
#pragma unroll
        for (int j = 0; j < 8; ++j) {
            const int k = c * 32 + fgrp * 8 + j;
            float v = 0.f;
            if (k < E_) v = (frow < 8) ? w_p[k] : (1.0f / (float)E_);
            wpf[c][j] = (short)f2bf(v);
        }
    }

    // per-lane A-operand rows (frow 0-7 = real state rows, 8-15 = zero row)
    const unsigned short* Mrow = (frow < 8) ? Ms + frow * HSTR : ZRs;
    const unsigned short* Xrow = (frow < 8) ? XEs + frow * HSTR : ZRs;
    const int xstep = (frow < 8) ? R_ * HSTR : 0;
    __syncthreads();

    // register-carried gh for the NEXT step (h_{-1}=0 -> gh(0)=0), spread layout
    float ghc[3][2] = {{0.f, 0.f}, {0.f, 0.f}, {0.f, 0.f}};

    for (int t = 0; t < T_; ++t) {
        unsigned short* Hw = (unsigned short*)(smraw + ((t & 1) ? L_HB : L_HA));
        const unsigned short* Hr = (const unsigned short*)(smraw + ((t & 1) ? L_HA : L_HB));
        const unsigned short* Hwrow = (frow < 8) ? (const unsigned short*)Hw + frow * HSTR : ZRs;

        // ===== chunk phase (every 8 steps): GX[t..t+7] = W_x @ x =====
        if ((t & 7) == 0) {
#pragma unroll
            for (int p = 0; p < 4; ++p) {
                const int i = tid + p * NT_;
                if (i < TCH * R_ * 31) {
                    const int mt = i / 248;
                    const int rem = i - mt * 248;
                    const int rr = rem / 31, q = rem - (rem / 31) * 31;
                    const int token = IDXs[rr * T_ + t + mt];
                    const int k = q * 4;
                    const float4 tv = *(const float4*)&tok[token * E_ + k];
                    const float4 pv = *(const float4*)&pos[(t + mt) * E_ + k];
#pragma unroll
                    for (int jj = 0; jj < 4; ++jj) {
                        const float x = ((const float*)&tv)[jj] + ((const float*)&pv)[jj];
                        XEs[(mt * R_ + rr) * HSTR + k + jj] = f2bf(x);
                    }
                }
            }
            __syncthreads();
#pragma unroll
            for (int g = 0; g < 3; ++g) {
                short8v bx[NKC];
#pragma unroll
                for (int c = 0; c < NKC; ++c)
                    bx[c] = *(const short8v*)&ws[WS_WX + ((g * 8 + wv) * NKC + c) * 512 + lane * 8];
                for (int mt = 0; mt < TCH; ++mt) {
                    float4v ax = (float4v){0.f, 0.f, 0.f, 0.f};
#pragma unroll
                    for (int c = 0; c < NKC; ++c) {
                        const short8v a = *(const short8v*)&Xrow[mt * xstep + c * 32 + fgrp * 8];
                        ax = __builtin_amdgcn_mfma_f32_16x16x32_bf16(a, bx[c], ax, 0, 0, 0);
                    }
                    if (actx) {
#pragma unroll
                        for (int j = 0; j < 4; ++j)
                            GXs[(mt * R_ + fgrp * 4 + j) * GXSTR + g * E_ + eo] = f2bf(ax[j]);
                    }
                }
            }
            // GX consumed lane-locally within the same fgrp-pair columns
        }

        // ===== phase A: gi_m MFMAs only (gh carried in regs) + gates -> h_new =====
        {
            short8v am[NKC];
#pragma unroll
            for (int c = 0; c < NKC; ++c)
                am[c] = *(const short8v*)&Mrow[c * 32 + fgrp * 8];
            float4v accm[3];
#pragma unroll
            for (int g = 0; g < 3; ++g) accm[g] = (float4v){0.f, 0.f, 0.f, 0.f};
#pragma unroll
            for (int g = 0; g < 3; ++g)
#pragma unroll
                for (int c = 0; c < NKC; ++c)
                    accm[g] = __builtin_amdgcn_mfma_f32_16x16x32_bf16(am[c], wm2f[g][c], accm[g], 0, 0, 0);
            // spread: fgrp2/3 receive partner's j=2,3 accumulators (xor-32)
            float am2[3][2];
#pragma unroll
            for (int g = 0; g < 3; ++g) {
                const float tm2 = __shfl_xor(accm[g][2], 32);
                const float tm3 = __shfl_xor(accm[g][3], 32);
                am2[g][0] = (fgrp < 2) ? accm[g][0] : tm2;
                am2[g][1] = (fgrp < 2) ? accm[g][1] : tm3;
            }
            if (eon) {
                const float brz0 = BRZs[eo], brz1 = BRZs[E_ + eo];
                const float bin = BINs[eo], bhn = BHNs[eo];
#pragma unroll
                for (int jj = 0; jj < 2; ++jj) {
                    const int r = rb + jj;
                    const unsigned short* gxp = &GXs[((t & 7) * R_ + r) * GXSTR];
                    const float rg = sigmoid_f(bf2f(gxp[eo]) + am2[0][jj] + ghc[0][jj] + brz0);
                    const float z = sigmoid_f(bf2f(gxp[E_ + eo]) + am2[1][jj] + ghc[1][jj] + brz1);
                    const float nn = tanh_f(bf2f(gxp[E2_ + eo]) + am2[2][jj] + bin + rg * (ghc[2][jj] + bhn));
                    const float hold = bf2f(Hr[r * HSTR + eo]);
                    const float hv = (1.0f - z) * nn + z * hold;
                    Hw[r * HSTR + eo] = f2bf(hv);
                }
            }
        }
        __syncthreads();

        // ===== phase C: cand+head+stats+gh(t+1) MFMAs, finalize/store =====
        {
            short8v ahw[NKC];
#pragma unroll
            for (int c = 0; c < NKC; ++c)
                ahw[c] = *(const short8v*)&Hwrow[c * 32 + fgrp * 8];

            float4v cc = (float4v){0.f, 0.f, 0.f, 0.f};
            float4v pm = (float4v){0.f, 0.f, 0.f, 0.f};
            float4v gr = (float4v){0.f, 0.f, 0.f, 0.f};
            float4v agh[3];
#pragma unroll
            for (int g = 0; g < 3; ++g) agh[g] = (float4v){0.f, 0.f, 0.f, 0.f};
#pragma unroll
            for (int c = 0; c < NKC; ++c) {
                cc = __builtin_amdgcn_mfma_f32_16x16x32_bf16(ahw[c], wmf[c], cc, 0, 0, 0);
                pm = __builtin_amdgcn_mfma_f32_16x16x32_bf16(ahw[c], wpf[c], pm, 0, 0, 0);
                gr = __builtin_amdgcn_mfma_f32_16x16x32_bf16(ahw[c], ahw[c], gr, 0, 0, 0);
#pragma unroll
                for (int g = 0; g < 3; ++g)
                    agh[g] = __builtin_amdgcn_mfma_f32_16x16x32_bf16(ahw[c], hhf[g][c], agh[g], 0, 0, 0);
            }
            float4v ad = (float4v){0.f, 0.f, 0.f, 0.f};
            if (hdw) {
#pragma unroll
                for (int c = 0; c < NKC; ++c)
                    ad = __builtin_amdgcn_mfma_f32_16x16x32_bf16(ahw[c], hdf[c], ad, 0, 0, 0);
            }

            // spread gh(t+1) into carried registers (2 rows/lane)
#pragma unroll
            for (int g = 0; g < 3; ++g) {
                const float tg2 = __shfl_xor(agh[g][2], 32);
                const float tg3 = __shfl_xor(agh[g][3], 32);
                ghc[g][0] = (fgrp < 2) ? agh[g][0] : tg2;
                ghc[g][1] = (fgrp < 2) ? agh[g][1] : tg3;
            }

            // spread regs j=2,3 to fgrp2/3 partners
            const float tc2 = __shfl_xor(cc[2], 32), tc3 = __shfl_xor(cc[3], 32);
            const float tp2 = __shfl_xor(pm[2], 32), tp3 = __shfl_xor(pm[3], 32);
            const float ta2 = __shfl_xor(ad[2], 32), ta3 = __shfl_xor(ad[3], 32);
            float ccl[2], pml[2], adl[2], s2l[2];
            ccl[0] = (fgrp < 2) ? cc[0] : tc2;
            ccl[1] = (fgrp < 2) ? cc[1] : tc3;
            pml[0] = (fgrp < 2) ? pm[0] : tp2;
            pml[1] = (fgrp < 2) ? pm[1] : tp3;
            adl[0] = (fgrp < 2) ? ad[0] : ta2;
            adl[1] = (fgrp < 2) ? ad[1] : ta3;
            {   // Gram diag for rows rb, rb+1
                const float d0a = __shfl(gr[0], 20 * (fgrp & 1) + 0);
                const float d1a = __shfl(gr[1], 20 * (fgrp & 1) + 1);
                const float d0b = __shfl(gr[2], 20 * (fgrp & 1) + 2);
                const float d1b = __shfl(gr[3], 20 * (fgrp & 1) + 3);
                s2l[0] = (fgrp < 2) ? d0a : d0b;
                s2l[1] = (fgrp < 2) ? d1a : d1b;
            }

            // finalize per-row stats; m update; head store — 2 rows/lane, all lanes
            const float bm = BMs[eon ? eo : 0];
            const float c1v = C1s[(hdw && vo < V_) ? vo : 0];
            const float c2v = C2Bs[(hdw && vo < V_) ? vo : 0];
#pragma unroll
            for (int jj = 0; jj < 2; ++jj) {
                const int r = rb + jj;
                const float other = __shfl_xor(pml[jj], 8);
                const float pdot = (frow < 8) ? pml[jj] : other;
                const float mu = (frow < 8) ? other : pml[jj];
                const float pv = sigmoid_f(pdot + bp);
                const float var = s2l[jj] * (1.0f / (float)E_) - mu * mu;
                const float rs = rsqrtf(var + 1e-5f);
                if (eon) {
                    const float cand = tanh_f(ccl[jj] + bm);
                    const float mold = bf2f(Ms[r * HSTR + eo]);
                    Ms[r * HSTR + eo] = f2bf((1.0f - pv) * mold + pv * cand);
                }
                if (hdw && vo < V_) {
                    const float lg = rs * (adl[jj] - mu * c1v) + c2v;
                    __builtin_nontemporal_store(
                        lg, &out[((size_t)(b0 + r) * T_ + t) * V_ + vo]);
                }
            }
        }
        __syncthreads();
    }
}

extern "C" void kernel_launch(void* const* d_in, const int* in_sizes, int n_in,
                              void* d_out, int out_size, void* d_ws, size_t ws_size,
                              hipStream_t stream) {
    const int* idx = (const int*)d_in[0];
    const float* tok = (const float*)d_in[1];
    const float* pos = (const float*)d_in[2];
    const float* w_ih = (const float*)d_in[3];
    const float* w_hh = (const float*)d_in[4];
    const float* b_ih = (const float*)d_in[5];
    const float* b_hh = (const float*)d_in[6];
    const float* w_p = (const float*)d_in[7];
    const float* b_p = (const float*)d_in[8];
    const float* w_m = (const float*)d_in[9];
    const float* b_m = (const float*)d_in[10];
    const float* ln_g = (const float*)d_in[11];
    const float* ln_b = (const float*)d_in[12];
    const float* w_head = (const float*)d_in[13];
    const float* b_head = (const float*)d_in[14];
    float* out = (float*)d_out;
    unsigned short* ws = (unsigned short*)d_ws;

    prep_weights<<<680, 256, 0, stream>>>(w_ih, w_hh, w_m, w_head, ln_g, ws);

    (void)hipFuncSetAttribute((const void*)gru_main,
                              hipFuncAttributeMaxDynamicSharedMemorySize,
                              SMEM_BYTES);
    gru_main<<<NB_, NT_, SMEM_BYTES, stream>>>(idx, tok, pos, b_ih, b_hh, w_p, b_p,
                                               b_m, ln_g, ln_b, w_head, b_head, ws, out);
}

// Round 20
// 684.323 us; speedup vs baseline: 1.5438x; 1.0041x over previous
//
#include <hip/hip_runtime.h>
#include <math.h>

// Problem constants
#define B_   2048
#define T_   256
#define E_   124
#define V_   65
#define E2_  248
#define R_   8               // batch rows per block (A rows 0-7; rows 8-15 zero)
#define NT_  512             // 8 waves
#define NB_  (B_ / R_)       // 256 blocks -> 1 per CU
#define NKC  4               // K chunks (124 padded to 128)
#define TCH  8               // timestep chunk for GX precompute

// ws offsets (unsigned shorts); identical to R13..R19 (validated)
#define WS_WX  0
#define WS_WM2 49152
#define WS_HH  98304
#define WS_WM  147456
#define WS_HD  163840               // W' = ln_g ∘ w_head
#define WS_END 174080

// LDS byte offsets (16B aligned); single-bf16 state, single H buffer
#define HSTR 136
#define GXSTR 376
#define L_M   0         // 2176
#define L_H   2176      // 2176 (single buffer: A writes, C reads)
#define L_ZR  4352      // 272 B zero row
#define L_GX  4624      // 48128 -> 52752
#define L_XE  52752     // 17408 -> 70160
#define L_BRZ 70160     // 248 f
#define L_BIN 71152
#define L_BHN 71648
#define L_BM  72144
#define L_WP  72640
#define L_C1  73136     // 68 f
#define L_C2B 73408     // 68 f
#define L_IDX 73680     // 8192
#define SMEM_BYTES 81872

typedef __attribute__((ext_vector_type(8))) short short8v;
typedef __attribute__((ext_vector_type(4))) float float4v;

__device__ __forceinline__ unsigned short f2bf(float x) {
    unsigned u = __float_as_uint(x);
    unsigned r = (u + 0x7fffu + ((u >> 16) & 1u)) >> 16;
    return (unsigned short)r;
}
__device__ __forceinline__ float bf2f(unsigned short s) {
    return __uint_as_float(((unsigned)s) << 16);
}
__device__ __forceinline__ float sigmoid_f(float x) {
    return 1.0f / (1.0f + __expf(-x));
}
__device__ __forceinline__ float tanh_f(float x) {
    return 2.0f / (1.0f + __expf(-2.0f * x)) - 1.0f;
}

// identical to R13..R19 (validated)
__global__ void prep_weights(const float* __restrict__ w_ih,
                             const float* __restrict__ w_hh,
                             const float* __restrict__ w_m,
                             const float* __restrict__ w_head,
                             const float* __restrict__ ln_g,
                             unsigned short* __restrict__ ws) {
    for (int n = blockIdx.x * blockDim.x + threadIdx.x; n < WS_END;
         n += gridDim.x * blockDim.x) {
        const int r9 = n & 511;
        const int lane = r9 >> 3, j = r9 & 7;
        const int krel = (lane >> 4) * 8 + j;   // 0..31
        const int colrel = lane & 15;
        float w = 0.f;
        if (n < WS_WM2) {                       // WX: w_ih[:, 0:124]
            const int blk = n >> 9;
            const int c = blk & 3, tt = (blk >> 2) & 7, g = blk >> 5;
            const int k = c * 32 + krel, e = tt * 16 + colrel;
            if (k < E_ && e < E_) w = w_ih[(g * E_ + e) * E2_ + k];
        } else if (n < WS_WM) {
            if (n < WS_HH) {                    // WM2: w_ih[:, 124:248]
                const int blk = (n - WS_WM2) >> 9;
                const int c = blk & 3, tt = (blk >> 2) & 7, g = blk >> 5;
                const int k = c * 32 + krel, e = tt * 16 + colrel;
                if (k < E_ && e < E_) w = w_ih[(g * E_ + e) * E2_ + E_ + k];
            } else {                            // HH: w_hh
                const int blk = (n - WS_HH) >> 9;
                const int c = blk & 3, tt = (blk >> 2) & 7, g = blk >> 5;
                const int k = c * 32 + krel, e = tt * 16 + colrel;
                if (k < E_ && e < E_) w = w_hh[(g * E_ + e) * E_ + k];
            }
        } else if (n < WS_HD) {                 // WM: w_m (cand)
            const int blk = (n - WS_WM) >> 9;
            const int c = blk & 3, tt = blk >> 2;
            const int k = c * 32 + krel, e = tt * 16 + colrel;
            if (k < E_ && e < E_) w = w_m[e * E_ + k];
        } else {                                // HD: W' = ln_g ∘ w_head
            const int blk = (n - WS_HD) >> 9;
            const int c = blk & 3, tt = blk >> 2;
            const int k = c * 32 + krel, v = tt * 16 + colrel;
            if (k < E_ && v < V_) w = w_head[v * E_ + k] * ln_g[k];
        }
        ws[n] = f2bf(w);
    }
}

__global__ void __launch_bounds__(NT_, 2)
gru_main(const int* __restrict__ idx, const float* __restrict__ tok,
         const float* __restrict__ pos,
         const float* __restrict__ b_ih, const float* __restrict__ b_hh,
         const float* __restrict__ w_p, const float* __restrict__ b_p,
         const float* __restrict__ b_m,
         const float* __restrict__ ln_g, const float* __restrict__ ln_b,
         const float* __restrict__ w_head, const float* __restrict__ b_head,
         const unsigned short* __restrict__ ws, float* __restrict__ out) {
    extern __shared__ char smraw[];
    unsigned short* Ms = (unsigned short*)(smraw + L_M);
    unsigned short* Hs = (unsigned short*)(smraw + L_H);
    unsigned short* ZRs = (unsigned short*)(smraw + L_ZR);
    unsigned short* GXs = (unsigned short*)(smraw + L_GX);
    unsigned short* XEs = (unsigned short*)(smraw + L_XE);
    float* BRZs = (float*)(smraw + L_BRZ);
    float* BINs = (float*)(smraw + L_BIN);
    float* BHNs = (float*)(smraw + L_BHN);
    float* BMs = (float*)(smraw + L_BM);
    float* WPs = (float*)(smraw + L_WP);
    float* C1s = (float*)(smraw + L_C1);
    float* C2Bs = (float*)(smraw + L_C2B);
    int* IDXs = (int*)(smraw + L_IDX);

    const int tid = threadIdx.x;
    const int lane = tid & 63;
    const int wv = tid >> 6;
    const int b0 = blockIdx.x * R_;
    const int frow = lane & 15;       // A row / C col
    const int fgrp = lane >> 4;       // k-group / C row-group
    const int eo = wv * 16 + frow;    // owned e (gate/cand column)
    const bool eon = (eo < E_);
    const bool actx = (fgrp < 2) && eon;        // chunk-phase GX writers
    const bool hdw = (wv >= 2) && (wv < 7);     // head waves
    const int vo = (wv - 2) * 16 + frow;        // head output col
    // lane-spread row base: fgrp0->{0,1} fgrp1->{4,5} fgrp2->{2,3} fgrp3->{6,7}
    const int rb = (fgrp < 2) ? fgrp * 4 : (fgrp - 2) * 4 + 2;

    // ---- one-time staging ----
    for (int i = tid; i < E2_; i += NT_) BRZs[i] = b_ih[i] + b_hh[i];
    for (int i = tid; i < E_; i += NT_) {
        BINs[i] = b_ih[E2_ + i];
        BHNs[i] = b_hh[E2_ + i];
        BMs[i] = b_m[i];
        WPs[i] = w_p[i];
    }
    for (int v = tid; v < V_; v += NT_) {       // LN-fold constants
        float s1 = 0.f, s2 = 0.f;
        for (int e = 0; e < E_; ++e) {
            const float w = w_head[v * E_ + e];
            s1 += ln_g[e] * w;
            s2 += ln_b[e] * w;
        }
        C1s[v] = s1;
        C2Bs[v] = s2 + b_head[v];
    }
    for (int i = tid; i < R_ * T_; i += NT_) IDXs[i] = idx[b0 * T_ + i];
    for (int i = tid; i < 2312; i += NT_) ((unsigned short*)smraw)[i] = 0;  // M,H,ZR
    for (int i = tid; i < TCH * R_ * HSTR; i += NT_) XEs[i] = 0;
    const float bp = b_p[0];

    // ---- permanent register caches ----
    short8v hhf[3][NKC], wm2f[3][NKC], wmf[NKC], hdf[NKC], wpf[NKC];
#pragma unroll
    for (int g = 0; g < 3; ++g)
#pragma unroll
        for (int c = 0; c < NKC; ++c) {
            hhf[g][c]  = *(const short8v*)&ws[WS_HH  + ((g * 8 + wv) * NKC + c) * 512 + lane * 8];
            wm2f[g][c] = *(const short8v*)&ws[WS_WM2 + ((g * 8 + wv) * NKC + c) * 512 + lane * 8];
        }
    {
        const int ht = hdw ? (wv - 2) : 0;
#pragma unroll
        for (int c = 0; c < NKC; ++c) {
            wmf[c] = *(const short8v*)&ws[WS_WM + (wv * NKC + c) * 512 + lane * 8];
            hdf[c] = *(const short8v*)&ws[WS_HD + (ht * NKC + c) * 512 + lane * 8];
        }
    }
    // stats B-frag: cols 0-7 = w_p[k], cols 8-15 = 1/E (k<124), else 0
#pragma unroll
    for (int c = 0; c < NKC; ++c) {
#pragma unroll
        for (int j = 0; j < 8; ++j) {
            const int k = c * 32 + fgrp * 8 + j;
            float v = 0.f;
            if (k < E_) v = (frow < 8) ? w_p[k] : (1.0f / (float)E_);
            wpf[c][j] = (short)f2bf(v);
        }
    }

    // per-lane A-operand rows (frow 0-7 = real state rows, 8-15 = zero row)
    const unsigned short* Mrow = (frow < 8) ? Ms + frow * HSTR : ZRs;
    const unsigned short* Hrow = (frow < 8) ? Hs + frow * HSTR : ZRs;
    const unsigned short* Xrow = (frow < 8) ? XEs + frow * HSTR : ZRs;
    const int xstep = (frow < 8) ? R_ * HSTR : 0;
    __syncthreads();

    // register-carried state (bit-exact: bf16-rounded values)
    float ghc[3][2] = {{0.f, 0.f}, {0.f, 0.f}, {0.f, 0.f}};  // gh(t), spread layout
    float hprev[2] = {0.f, 0.f};   // h(t-1)[rb+jj][eo]
    float mprev[2] = {0.f, 0.f};   // m(t-1)[rb+jj][eo]

    for (int t = 0; t < T_; ++t) {
        // ===== chunk phase (every 8 steps): GX[t..t+7] = W_x @ x =====
        if ((t & 7) == 0) {
#pragma unroll
            for (int p = 0; p < 4; ++p) {
                const int i = tid + p * NT_;
                if (i < TCH * R_ * 31) {
                    const int mt = i / 248;
                    const int rem = i - mt * 248;
                    const int rr = rem / 31, q = rem - (rem / 31) * 31;
                    const int token = IDXs[rr * T_ + t + mt];
                    const int k = q * 4;
                    const float4 tv = *(const float4*)&tok[token * E_ + k];
                    const float4 pv = *(const float4*)&pos[(t + mt) * E_ + k];
#pragma unroll
                    for (int jj = 0; jj < 4; ++jj) {
                        const float x = ((const float*)&tv)[jj] + ((const float*)&pv)[jj];
                        XEs[(mt * R_ + rr) * HSTR + k + jj] = f2bf(x);
                    }
                }
            }
            __syncthreads();
#pragma unroll
            for (int g = 0; g < 3; ++g) {
                short8v bx[NKC];
#pragma unroll
                for (int c = 0; c < NKC; ++c)
                    bx[c] = *(const short8v*)&ws[WS_WX + ((g * 8 + wv) * NKC + c) * 512 + lane * 8];
                for (int mt = 0; mt < TCH; ++mt) {
                    float4v ax = (float4v){0.f, 0.f, 0.f, 0.f};
#pragma unroll
                    for (int c = 0; c < NKC; ++c) {
                        const short8v a = *(const short8v*)&Xrow[mt * xstep + c * 32 + fgrp * 8];
                        ax = __builtin_amdgcn_mfma_f32_16x16x32_bf16(a, bx[c], ax, 0, 0, 0);
                    }
                    if (actx) {
#pragma unroll
                        for (int j = 0; j < 4; ++j)
                            GXs[(mt * R_ + fgrp * 4 + j) * GXSTR + g * E_ + eo] = f2bf(ax[j]);
                    }
                }
            }
            // GX consumed lane-locally within the same fgrp-pair columns
        }

        // ===== phase A: GX prefetch, gi_m MFMAs (gh carried), gates -> h =====
        {
            // GX prefetch first: latency hides under the MFMA chain
            float gx[2][3];
#pragma unroll
            for (int jj = 0; jj < 2; ++jj) {
                const unsigned short* gxp = &GXs[((t & 7) * R_ + rb + jj) * GXSTR];
                gx[jj][0] = bf2f(gxp[eo]);
                gx[jj][1] = bf2f(gxp[E_ + eo]);
                gx[jj][2] = bf2f(gxp[E2_ + eo]);
            }
            short8v am[NKC];
#pragma unroll
            for (int c = 0; c < NKC; ++c)
                am[c] = *(const short8v*)&Mrow[c * 32 + fgrp * 8];
            float4v accm[3];
#pragma unroll
            for (int g = 0; g < 3; ++g) accm[g] = (float4v){0.f, 0.f, 0.f, 0.f};
#pragma unroll
            for (int g = 0; g < 3; ++g)
#pragma unroll
                for (int c = 0; c < NKC; ++c)
                    accm[g] = __builtin_amdgcn_mfma_f32_16x16x32_bf16(am[c], wm2f[g][c], accm[g], 0, 0, 0);
            // spread: fgrp2/3 receive partner's j=2,3 accumulators (xor-32)
            float am2[3][2];
#pragma unroll
            for (int g = 0; g < 3; ++g) {
                const float tm2 = __shfl_xor(accm[g][2], 32);
                const float tm3 = __shfl_xor(accm[g][3], 32);
                am2[g][0] = (fgrp < 2) ? accm[g][0] : tm2;
                am2[g][1] = (fgrp < 2) ? accm[g][1] : tm3;
            }
            if (eon) {
                const float brz0 = BRZs[eo], brz1 = BRZs[E_ + eo];
                const float bin = BINs[eo], bhn = BHNs[eo];
#pragma unroll
                for (int jj = 0; jj < 2; ++jj) {
                    const int r = rb + jj;
                    const float rg = sigmoid_f(gx[jj][0] + am2[0][jj] + ghc[0][jj] + brz0);
                    const float z = sigmoid_f(gx[jj][1] + am2[1][jj] + ghc[1][jj] + brz1);
                    const float nn = tanh_f(gx[jj][2] + am2[2][jj] + bin + rg * (ghc[2][jj] + bhn));
                    const float hv = (1.0f - z) * nn + z * hprev[jj];
                    const unsigned short h1 = f2bf(hv);
                    hprev[jj] = bf2f(h1);   // carry the bf16-rounded value (bit-exact)
                    Hs[r * HSTR + eo] = h1;
                }
            }
        }
        __syncthreads();

        // ===== phase C: cand+head+stats+gh(t+1) MFMAs, finalize/store =====
        {
            short8v ahw[NKC];
#pragma unroll
            for (int c = 0; c < NKC; ++c)
                ahw[c] = *(const short8v*)&Hrow[c * 32 + fgrp * 8];

            float4v cc = (float4v){0.f, 0.f, 0.f, 0.f};
            float4v pm = (float4v){0.f, 0.f, 0.f, 0.f};
            float4v gr = (float4v){0.f, 0.f, 0.f, 0.f};
            float4v agh[3];
#pragma unroll
            for (int g = 0; g < 3; ++g) agh[g] = (float4v){0.f, 0.f, 0.f, 0.f};
#pragma unroll
            for (int c = 0; c < NKC; ++c) {
                cc = __builtin_amdgcn_mfma_f32_16x16x32_bf16(ahw[c], wmf[c], cc, 0, 0, 0);
                pm = __builtin_amdgcn_mfma_f32_16x16x32_bf16(ahw[c], wpf[c], pm, 0, 0, 0);
                gr = __builtin_amdgcn_mfma_f32_16x16x32_bf16(ahw[c], ahw[c], gr, 0, 0, 0);
#pragma unroll
                for (int g = 0; g < 3; ++g)
                    agh[g] = __builtin_amdgcn_mfma_f32_16x16x32_bf16(ahw[c], hhf[g][c], agh[g], 0, 0, 0);
            }
            float4v ad = (float4v){0.f, 0.f, 0.f, 0.f};
            if (hdw) {
#pragma unroll
                for (int c = 0; c < NKC; ++c)
                    ad = __builtin_amdgcn_mfma_f32_16x16x32_bf16(ahw[c], hdf[c], ad, 0, 0, 0);
            }

            // spread gh(t+1) into carried registers (2 rows/lane)
#pragma unroll
            for (int g = 0; g < 3; ++g) {
                const float tg2 = __shfl_xor(agh[g][2], 32);
                const float tg3 = __shfl_xor(agh[g][3], 32);
                ghc[g][0] = (fgrp < 2) ? agh[g][0] : tg2;
                ghc[g][1] = (fgrp < 2) ? agh[g][1] : tg3;
            }

            // spread regs j=2,3 to fgrp2/3 partners
            const float tc2 = __shfl_xor(cc[2], 32), tc3 = __shfl_xor(cc[3], 32);
            const float tp2 = __shfl_xor(pm[2], 32), tp3 = __shfl_xor(pm[3], 32);
            const float ta2 = __shfl_xor(ad[2], 32), ta3 = __shfl_xor(ad[3], 32);
            float ccl[2], pml[2], adl[2], s2l[2];
            ccl[0] = (fgrp < 2) ? cc[0] : tc2;
            ccl[1] = (fgrp < 2) ? cc[1] : tc3;
            pml[0] = (fgrp < 2) ? pm[0] : tp2;
            pml[1] = (fgrp < 2) ? pm[1] : tp3;
            adl[0] = (fgrp < 2) ? ad[0] : ta2;
            adl[1] = (fgrp < 2) ? ad[1] : ta3;
            {   // Gram diag for rows rb, rb+1
                const float d0a = __shfl(gr[0], 20 * (fgrp & 1) + 0);
                const float d1a = __shfl(gr[1], 20 * (fgrp & 1) + 1);
                const float d0b = __shfl(gr[2], 20 * (fgrp & 1) + 2);
                const float d1b = __shfl(gr[3], 20 * (fgrp & 1) + 3);
                s2l[0] = (fgrp < 2) ? d0a : d0b;
                s2l[1] = (fgrp < 2) ? d1a : d1b;
            }

            // finalize per-row stats; m update (reg-carried); head store
            const float bm = BMs[eon ? eo : 0];
            const float c1v = C1s[(hdw && vo < V_) ? vo : 0];
            const float c2v = C2Bs[(hdw && vo < V_) ? vo : 0];
#pragma unroll
            for (int jj = 0; jj < 2; ++jj) {
                const int r = rb + jj;
                const float other = __shfl_xor(pml[jj], 8);
                const float pdot = (frow < 8) ? pml[jj] : other;
                const float mu = (frow < 8) ? other : pml[jj];
                const float pv = sigmoid_f(pdot + bp);
                const float var = s2l[jj] * (1.0f / (float)E_) - mu * mu;
                const float rs = rsqrtf(var + 1e-5f);
                if (eon) {
                    const float cand = tanh_f(ccl[jj] + bm);
                    const float mnew = (1.0f - pv) * mprev[jj] + pv * cand;
                    const unsigned short m1 = f2bf(mnew);
                    mprev[jj] = bf2f(m1);   // bit-exact carry
                    Ms[r * HSTR + eo] = m1;
                }
                if (hdw && vo < V_) {
                    const float lg = rs * (adl[jj] - mu * c1v) + c2v;
                    __builtin_nontemporal_store(
                        lg, &out[((size_t)(b0 + r) * T_ + t) * V_ + vo]);
                }
            }
        }
        __syncthreads();
    }
}

extern "C" void kernel_launch(void* const* d_in, const int* in_sizes, int n_in,
                              void* d_out, int out_size, void* d_ws, size_t ws_size,
                              hipStream_t stream) {
    const int* idx = (const int*)d_in[0];
    const float* tok = (const float*)d_in[1];
    const float* pos = (const float*)d_in[2];
    const float* w_ih = (const float*)d_in[3];
    const float* w_hh = (const float*)d_in[4];
    const float* b_ih = (const float*)d_in[5];
    const float* b_hh = (const float*)d_in[6];
    const float* w_p = (const float*)d_in[7];
    const float* b_p = (const float*)d_in[8];
    const float* w_m = (const float*)d_in[9];
    const float* b_m = (const float*)d_in[10];
    const float* ln_g = (const float*)d_in[11];
    const float* ln_b = (const float*)d_in[12];
    const float* w_head = (const float*)d_in[13];
    const float* b_head = (const float*)d_in[14];
    float* out = (float*)d_out;
    unsigned short* ws = (unsigned short*)d_ws;

    prep_weights<<<680, 256, 0, stream>>>(w_ih, w_hh, w_m, w_head, ln_g, ws);

    (void)hipFuncSetAttribute((const void*)gru_main,
                              hipFuncAttributeMaxDynamicSharedMemorySize,
                              SMEM_BYTES);
    gru_main<<<NB_, NT_, SMEM_BYTES, stream>>>(idx, tok, pos, b_ih, b_hh, w_p, b_p,
                                               b_m, ln_g, ln_b, w_head, b_head, ws, out);
}